// Round 3
// baseline (323.771 us; speedup 1.0000x reference)
//
#include <hip/hip_runtime.h>
#include <hip/hip_cooperative_groups.h>

namespace cg = cooperative_groups;

// Workspace layout (float offsets)
#define WS_M      0        // Mt[r*100+p] = (w_lin2 @ w_lin1)^T, 10000 floats
#define WS_K      10000    // K[c][a][b][ci][u][v], 2646 floats
#define WS_BETA   12646    // beta[c][a][b], 18 floats
#define WS_W9     12664    // W9[c][ci][dy][dx], 486 floats
#define WS_BT     13150    // beta_tot[c] (interior combined bias), 2 floats
#define WS_INI    16384    // ini[b][c][h][w], 1,638,400 floats
#define WS_UIT    (16384 + 1638400)      // uiL[bc][l][p128] bf16, 2,097,152 ushorts
#define WS_UFT    (16384 + 2*1638400)    // ufL[bc][l][p128] bf16

typedef short bf16x8 __attribute__((ext_vector_type(8)));
typedef float f32x4  __attribute__((ext_vector_type(4)));

__device__ inline ushort f2bf(float f) {   // round-to-nearest-even
    unsigned u = __float_as_uint(f);
    unsigned r = (u + 0x7fffu + ((u >> 16) & 1u)) >> 16;
    return (ushort)r;
}

#define SPS 68

// ===========================================================================
// Single cooperative mega-kernel: phases P (prep) -> C (conv+border) ->
// T (trans both modes, pg-merged) -> A (att), separated by grid.sync().
// LDS is a 47.2 KB union -> 3 blocks/CU; launch_bounds(256,3) caps VGPR<=168.
// All cross-phase reads use VECTOR loads (grid.sync acquire invalidates vL1;
// avoids scalar-cache staleness for data written by other blocks this launch).
// ===========================================================================
__global__ __launch_bounds__(256, 3) void k_all(
    const float* __restrict__ x,
    const float* __restrict__ wl1, const float* __restrict__ wl2,
    const float* __restrict__ wc1, const float* __restrict__ bc1,
    const float* __restrict__ wc2, const float* __restrict__ bc2,
    const float* __restrict__ wfm, const float* __restrict__ bfm,
    float* __restrict__ ws, float* __restrict__ out)
{
    union alignas(16) SMem {
        struct { float sx[3][40][40]; float sW9[486]; float sBt[2]; } conv;   // 21,152 B
        struct { float sM[5000]; float sP[100 * SPS]; } trans;                // 47,200 B
        struct { float swc1[9408]; float swc2[1152]; float sBeta[18]; } prep; // 42,312 B
    };
    __shared__ SMem sm;

    const int blk = blockIdx.x, t = threadIdx.x, nblk = gridDim.x;
    float*  Mt   = ws + WS_M;
    float*  Kw   = ws + WS_K;
    float*  Beta = ws + WS_BETA;
    float*  W9   = ws + WS_W9;
    float*  Bt   = ws + WS_BT;
    float*  ini  = ws + WS_INI;
    ushort* uiL  = (ushort*)(ws + WS_UIT);
    ushort* ufL  = (ushort*)(ws + WS_UFT);

    // ---------------- Phase P: prep (blocks 0..44; others pass through) ----
    if (blk < 40) {
        // M[p][r] = sum_q wl2[p,q]*wl1[q,r]; stored transposed Mt[r*100+p]
        int idx = blk * 256 + t;
        if (idx < 10000) {
            int p = idx / 100, r = idx % 100;
            float s = 0.f;
            for (int q = 0; q < 200; ++q)
                s += wl2[p * 200 + q] * wl1[q * 100 + r];
            Mt[r * 100 + p] = s;
        }
    } else if (blk < 45) {
        for (int i = t; i < 9408; i += 256) sm.prep.swc1[i] = wc1[i];
        for (int i = t; i < 1152; i += 256) sm.prep.swc2[i] = wc2[i];
        __syncthreads();
        if (blk < 43) {
            int base = (blk - 40) * 882;
            for (int ii = t; ii < 882; ii += 256) {
                int idx = base + ii;
                int v = idx % 7; int t1 = idx / 7;
                int u = t1 % 7;  int t2 = t1 / 7;
                int ci = t2 % 3; int t3 = t2 / 3;
                int b = t3 % 3;  int t4 = t3 / 3;
                int a = t4 % 3;  int c = t4 / 3;
                float s = 0.f;
                for (int c64 = 0; c64 < 64; ++c64)
                    s += sm.prep.swc2[((c * 64 + c64) * 3 + a) * 3 + b] *
                         sm.prep.swc1[((c64 * 3 + ci) * 7 + u) * 7 + v];
                Kw[idx] = s;
            }
            if (blk == 40) {
                if (t < 18) {
                    int b = t % 3; int a = (t / 3) % 3; int c = t / 9;
                    float s = 0.f;
                    for (int c64 = 0; c64 < 64; ++c64)
                        s += sm.prep.swc2[((c * 64 + c64) * 3 + a) * 3 + b] * bc1[c64];
                    sm.prep.sBeta[t] = s; Beta[t] = s;
                }
                __syncthreads();
                if (t < 2) {
                    float s = bc2[t];
                    for (int j2 = 0; j2 < 9; ++j2) s += sm.prep.sBeta[t * 9 + j2];
                    Bt[t] = s;
                }
            }
        } else {
            // W9[c][ci][dy][dx] = sum_{a,b valid} sum_c64 wc2[c,c64,a,b]*wc1[c64,ci,dy-a,dx-b]
            int idx = (blk - 43) * 243 + t;
            if (t < 243) {
                int dx = idx % 9; int t1 = idx / 9;
                int dy = t1 % 9;  int t2 = t1 / 9;
                int ci = t2 % 3;  int c = t2 / 3;
                float s = 0.f;
                for (int a = 0; a < 3; ++a) {
                    int u = dy - a; if (u < 0 || u > 6) continue;
                    for (int b = 0; b < 3; ++b) {
                        int v = dx - b; if (v < 0 || v > 6) continue;
                        for (int c64 = 0; c64 < 64; ++c64)
                            s += sm.prep.swc2[((c * 64 + c64) * 3 + a) * 3 + b] *
                                 sm.prep.swc1[((c64 * 3 + ci) * 7 + u) * 7 + v];
                    }
                }
                W9[idx] = s;   // layout c*243 + ci*81 + dy*9 + dx
            }
        }
    }
    cg::this_grid().sync();

    // ---------------- Phase C: interior conv + exact border ----------------
    for (int u = blk; u < 3352; u += nblk) {
        if (u < 800) {
            int b = u / 100, by = (u / 10) % 10, bx = u % 10;
            int gh0 = by * 32, gw0 = bx * 32;
            __syncthreads();   // protect LDS from previous unit's readers
            for (int idx = t; idx < 3 * 40 * 40; idx += 256) {
                int ci = idx / 1600;
                int rem = idx - ci * 1600;
                int rr = rem / 40, cc = rem - rr * 40;
                int gh = gh0 - 4 + rr, gw = gw0 - 4 + cc;
                float v = 0.f;
                if ((unsigned)gh < 320u && (unsigned)gw < 320u)
                    v = x[(b * 3 + ci) * 102400 + gh * 320 + gw];
                sm.conv.sx[ci][rr][cc] = v;
            }
            for (int i = t; i < 486; i += 256) sm.conv.sW9[i] = W9[i];
            if (t < 2) sm.conv.sBt[t] = Bt[t];
            __syncthreads();
            int r = t >> 3, cg4 = t & 7;
            int h = gh0 + r, w0c = gw0 + cg4 * 4;
            float acc0[4], acc1[4];
            float bt0 = sm.conv.sBt[0], bt1 = sm.conv.sBt[1];
            #pragma unroll
            for (int j = 0; j < 4; ++j) { acc0[j] = bt0; acc1[j] = bt1; }
            #pragma unroll
            for (int ci = 0; ci < 3; ++ci) {
                #pragma unroll
                for (int dy = 0; dy < 9; ++dy) {
                    const float* xr = &sm.conv.sx[ci][r + dy][cg4 * 4];
                    float4 xa = *(const float4*)(xr);
                    float4 xb = *(const float4*)(xr + 4);
                    float4 xc = *(const float4*)(xr + 8);
                    float xv[12] = {xa.x, xa.y, xa.z, xa.w,
                                    xb.x, xb.y, xb.z, xb.w,
                                    xc.x, xc.y, xc.z, xc.w};
                    #pragma unroll
                    for (int dx = 0; dx < 9; ++dx) {
                        float w0t = sm.conv.sW9[ci * 81 + dy * 9 + dx];
                        float w1t = sm.conv.sW9[243 + ci * 81 + dy * 9 + dx];
                        #pragma unroll
                        for (int j = 0; j < 4; ++j) {
                            acc0[j] += w0t * xv[dx + j];
                            acc1[j] += w1t * xv[dx + j];
                        }
                    }
                }
            }
            size_t obase = (size_t)(b * 2) * 102400 + h * 320 + w0c;
            bool edge = (by == 0) | (by == 9) | (bx == 0) | (bx == 9);
            if (!edge) {
                *(float4*)&ini[obase] = make_float4(acc0[0], acc0[1], acc0[2], acc0[3]);
                *(float4*)&ini[obase + 102400] = make_float4(acc1[0], acc1[1], acc1[2], acc1[3]);
            } else {
                bool rring = (h == 0) | (h == 319);
                #pragma unroll
                for (int j = 0; j < 4; ++j) {
                    int w = w0c + j;
                    if (!rring && w != 0 && w != 319) {
                        ini[obase + j] = acc0[j];
                        ini[obase + 102400 + j] = acc1[j];
                    }
                }
            }
        } else {
            // exact border ring: one wave per pixel, both channels
            int witem = (u - 800) * 4 + (t >> 6);   // 0..10207 = 8 b * 1276 px
            int lane = t & 63;
            int b = witem / 1276, j = witem % 1276;
            int h, w;
            if (j < 320)      { h = 0;           w = j; }
            else if (j < 640) { h = 319;         w = j - 320; }
            else if (j < 958) { h = 1 + j - 640; w = 0; }
            else              { h = 1 + j - 958; w = 319; }
            float acc0 = 0.f, acc1 = 0.f;
            #pragma unroll
            for (int rep = 0; rep < 3; ++rep) {
                int e = lane + rep * 64;
                if (e < 189) {
                    int a = e / 63;    int rem  = e - a * 63;
                    int bb = rem / 21; int rem2 = rem - bb * 21;
                    int ci = rem2 / 7; int uu = rem2 - ci * 7;
                    int hh0 = h + a - 1;
                    int ww0 = w + bb - 1;
                    bool abv = ((unsigned)hh0 < 320u) & ((unsigned)ww0 < 320u);
                    if (abv && ci == 0 && uu == 0) {
                        acc0 += Beta[a * 3 + bb];
                        acc1 += Beta[9 + a * 3 + bb];
                    }
                    int hx = hh0 + uu - 3;
                    if (abv && (unsigned)hx < 320u) {
                        const float* Kc = Kw + (a * 9 + bb * 3 + ci) * 49 + uu * 7;  // c=0
                        const float* xr = x + (b * 3 + ci) * 102400 + hx * 320;
                        #pragma unroll
                        for (int v = 0; v < 7; ++v) {
                            int wx = ww0 + v - 3;
                            if ((unsigned)wx < 320u) {
                                float xv = xr[wx];
                                acc0 += Kc[v] * xv;
                                acc1 += Kc[1323 + v] * xv;
                            }
                        }
                    }
                }
            }
            #pragma unroll
            for (int off = 32; off > 0; off >>= 1) {
                acc0 += __shfl_down(acc0, off, 64);
                acc1 += __shfl_down(acc1, off, 64);
            }
            if (lane == 0) {
                size_t pb = (size_t)(b * 2) * 102400 + h * 320 + w;
                ini[pb] = acc0 + bc2[0];
                ini[pb + 102400] = acc1 + bc2[1];
            }
        }
    }
    cg::this_grid().sync();

    // ---------------- Phase T: trans, unit = (bc, lg, mode); pg merged -----
    for (int u = blk; u < 512; u += nblk) {
        int bc = u & 15, lg = (u >> 4) & 15, mode = u >> 8;
        ushort* outL = mode ? ufL : uiL;
        __syncthreads();   // reuse guard
        for (int i = t; i < 5000; i += 256) {        // sM for pg=0
            int r = i / 50, p = i % 50;
            sm.trans.sM[i] = Mt[r * 100 + p];
        }
        int b = bc >> 1, c = bc & 1;
        int row0 = lg * 20;
        if (mode == 0) {
            for (int e = t; e < 6400; e += 256) {
                int irow = e / 320, col = e % 320;
                int off = (row0 + irow) * 320 + col;
                float val = ini[bc * 102400 + off];
                int li = (irow / 10) * 32 + col / 10;
                int r  = (irow % 10) * 10 + col % 10;
                sm.trans.sP[r * SPS + li] = val;
            }
        } else {
            float wf0 = wfm[c * 3 + 0], wf1 = wfm[c * 3 + 1], wf2 = wfm[c * 3 + 2];
            float bfv = bfm[c];
            for (int e = t; e < 6400; e += 256) {
                int irow = e / 320, col = e % 320;
                int off = (row0 + irow) * 320 + col;
                float val = (bfv + x[(b * 3 + 0) * 102400 + off] * wf0
                                 + x[(b * 3 + 1) * 102400 + off] * wf1
                                 + x[(b * 3 + 2) * 102400 + off] * wf2) * 0.25f;
                int li = (irow / 10) * 32 + col / 10;
                int r  = (irow % 10) * 10 + col % 10;
                sm.trans.sP[r * SPS + li] = val;
            }
        }
        for (int e = t; e < 64 * 7; e += 256) {      // zero p-pad [100,128)
            int l = lg * 64 + e / 7, q = e % 7;
            *(uint2*)&outL[((size_t)bc * 1024 + l) * 128 + 100 + q * 4] = make_uint2(0u, 0u);
        }
        __syncthreads();
        auto trans_compute = [&](int pgoff) {
            if (t < 200) {
                int py = t / 8, lx = t % 8;
                int p0 = py * 2, lo = lx * 8;
                float acc[2][8];
                #pragma unroll
                for (int i = 0; i < 2; ++i)
                    #pragma unroll
                    for (int j = 0; j < 8; ++j) acc[i][j] = 0.f;
                for (int r = 0; r < 100; ++r) {
                    float2 a  = *(const float2*)&sm.trans.sM[r * 50 + p0];
                    float4 b0 = *(const float4*)&sm.trans.sP[r * SPS + lo];
                    float4 b1 = *(const float4*)&sm.trans.sP[r * SPS + lo + 4];
                    float av[2] = {a.x, a.y};
                    float bv[8] = {b0.x, b0.y, b0.z, b0.w, b1.x, b1.y, b1.z, b1.w};
                    #pragma unroll
                    for (int i = 0; i < 2; ++i)
                        #pragma unroll
                        for (int j = 0; j < 8; ++j)
                            acc[i][j] += av[i] * bv[j];
                }
                int pbase = pgoff + p0;   // even -> 4B-aligned ushort2 store
                #pragma unroll
                for (int j = 0; j < 8; ++j) {
                    int l = lg * 64 + lo + j;
                    unsigned v0 = f2bf(fmaxf(acc[0][j], 0.f));
                    unsigned v1 = f2bf(fmaxf(acc[1][j], 0.f));
                    *(unsigned*)&outL[((size_t)bc * 1024 + l) * 128 + pbase] = v0 | (v1 << 16);
                }
            }
        };
        trans_compute(0);
        __syncthreads();
        for (int i = t; i < 5000; i += 256) {        // sM for pg=1
            int r = i / 50, p = i % 50;
            sm.trans.sM[i] = Mt[r * 100 + 50 + p];
        }
        __syncthreads();
        trans_compute(50);
    }
    cg::this_grid().sync();

    // ---------------- Phase A: att, unit = 64-row x 128-col tile -----------
    // 2048 units = 16 bc x (16 row-strips x 8 col-blocks). 4 waves 2x2,
    // each wave 32x64 = 2x4 mfma tiles.
    for (int u = blk; u < 2048; u += nblk) {
        int bca  = u >> 7;
        int rem  = u & 127;
        int row0 = (rem >> 3) * 64;
        int col0 = (rem & 7) * 128;
        int wave = t >> 6, lane = t & 63;
        int r0 = row0 + (wave >> 1) * 32;
        int c0 = col0 + (wave & 1) * 64;
        int m = lane & 15, quad = lane >> 4;
        const ushort* ub = uiL + (size_t)bca * 131072;
        const ushort* vb = ufL + (size_t)bca * 131072;
        f32x4 acc[2][4];
        #pragma unroll
        for (int i = 0; i < 2; ++i)
            #pragma unroll
            for (int j = 0; j < 4; ++j)
                acc[i][j] = (f32x4){0.f, 0.f, 0.f, 0.f};
        #pragma unroll
        for (int k0 = 0; k0 < 128; k0 += 32) {
            bf16x8 af[2], bfr[4];
            #pragma unroll
            for (int i = 0; i < 2; ++i)
                af[i] = *(const bf16x8*)&ub[(size_t)(r0 + i * 16 + m) * 128 + k0 + quad * 8];
            #pragma unroll
            for (int j = 0; j < 4; ++j)
                bfr[j] = *(const bf16x8*)&vb[(size_t)(c0 + j * 16 + m) * 128 + k0 + quad * 8];
            #pragma unroll
            for (int i = 0; i < 2; ++i)
                #pragma unroll
                for (int j = 0; j < 4; ++j)
                    acc[i][j] = __builtin_amdgcn_mfma_f32_16x16x32_bf16(af[i], bfr[j], acc[i][j], 0, 0, 0);
        }
        // C/D: col = lane&15, row = quad*4 + reg (m89/m91-verified)
        #pragma unroll
        for (int i = 0; i < 2; ++i) {
            #pragma unroll
            for (int r = 0; r < 4; ++r) {
                int row = r0 + i * 16 + quad * 4 + r;
                float* o = out + ((size_t)bca * 1024 + row) * 1024;
                #pragma unroll
                for (int j = 0; j < 4; ++j)
                    o[c0 + j * 16 + m] = acc[i][j][r] * 0.01f;
            }
        }
    }
}

// ===========================================================================
// Fallback path: the proven 4-kernel pipeline (Round-2, 170 us), used only
// if the cooperative launch is rejected by the runtime / capture.
// ===========================================================================
__global__ __launch_bounds__(256) void k_prep(const float* __restrict__ wl1,
                                              const float* __restrict__ wl2,
                                              const float* __restrict__ wc1,
                                              const float* __restrict__ bc1,
                                              const float* __restrict__ wc2,
                                              const float* __restrict__ bc2,
                                              float* __restrict__ ws) {
    int blk = blockIdx.x;
    int t = threadIdx.x;
    if (blk < 40) {
        int idx = blk * 256 + t;
        if (idx < 10000) {
            int p = idx / 100, r = idx % 100;
            float s = 0.f;
            for (int q = 0; q < 200; ++q)
                s += wl2[p * 200 + q] * wl1[q * 100 + r];
            ws[WS_M + r * 100 + p] = s;
        }
        return;
    }
    __shared__ float swc1[9408];
    __shared__ float swc2[1152];
    __shared__ float sBeta[18];
    for (int i = t; i < 9408; i += 256) swc1[i] = wc1[i];
    for (int i = t; i < 1152; i += 256) swc2[i] = wc2[i];
    __syncthreads();
    if (blk < 43) {
        int base = (blk - 40) * 882;
        for (int ii = t; ii < 882; ii += 256) {
            int idx = base + ii;
            int v = idx % 7; int t1 = idx / 7;
            int u = t1 % 7;  int t2 = t1 / 7;
            int ci = t2 % 3; int t3 = t2 / 3;
            int b = t3 % 3;  int t4 = t3 / 3;
            int a = t4 % 3;  int c = t4 / 3;
            float s = 0.f;
            for (int c64 = 0; c64 < 64; ++c64)
                s += swc2[((c * 64 + c64) * 3 + a) * 3 + b] *
                     swc1[((c64 * 3 + ci) * 7 + u) * 7 + v];
            ws[WS_K + idx] = s;
        }
        if (blk == 40) {
            if (t < 18) {
                int b = t % 3; int a = (t / 3) % 3; int c = t / 9;
                float s = 0.f;
                for (int c64 = 0; c64 < 64; ++c64)
                    s += swc2[((c * 64 + c64) * 3 + a) * 3 + b] * bc1[c64];
                sBeta[t] = s; ws[WS_BETA + t] = s;
            }
            __syncthreads();
            if (t < 2) {
                float s = bc2[t];
                for (int j2 = 0; j2 < 9; ++j2) s += sBeta[t * 9 + j2];
                ws[WS_BT + t] = s;
            }
        }
    } else {
        int idx = (blk - 43) * 243 + t;
        if (t < 243) {
            int dx = idx % 9; int t1 = idx / 9;
            int dy = t1 % 9;  int t2 = t1 / 9;
            int ci = t2 % 3;  int c = t2 / 3;
            float s = 0.f;
            for (int a = 0; a < 3; ++a) {
                int u = dy - a; if (u < 0 || u > 6) continue;
                for (int b = 0; b < 3; ++b) {
                    int v = dx - b; if (v < 0 || v > 6) continue;
                    for (int c64 = 0; c64 < 64; ++c64)
                        s += swc2[((c * 64 + c64) * 3 + a) * 3 + b] *
                             swc1[((c64 * 3 + ci) * 7 + u) * 7 + v];
                }
            }
            ws[WS_W9 + idx] = s;
        }
    }
}

__global__ __launch_bounds__(256) void k_convb(const float* __restrict__ x,
                                               const float* __restrict__ bc2,
                                               const float* __restrict__ ws,
                                               float* __restrict__ ini) {
    __shared__ float sx[3][40][40];
    int bid = blockIdx.x;
    int t = threadIdx.x;
    if (bid < 800) {
        int b = bid / 100, by = (bid / 10) % 10, bx = bid % 10;
        int gh0 = by * 32, gw0 = bx * 32;
        for (int idx = t; idx < 3 * 40 * 40; idx += 256) {
            int ci = idx / 1600;
            int rem = idx - ci * 1600;
            int rr = rem / 40, cc = rem - rr * 40;
            int gh = gh0 - 4 + rr, gw = gw0 - 4 + cc;
            float v = 0.f;
            if ((unsigned)gh < 320u && (unsigned)gw < 320u)
                v = x[(b * 3 + ci) * 102400 + gh * 320 + gw];
            sx[ci][rr][cc] = v;
        }
        __syncthreads();
        const float* W9g = ws + WS_W9;
        const float* Btg = ws + WS_BT;
        int r = t >> 3, cg4 = t & 7;
        int h = gh0 + r, w0c = gw0 + cg4 * 4;
        float acc0[4], acc1[4];
        float bt0 = Btg[0], bt1 = Btg[1];
        #pragma unroll
        for (int j = 0; j < 4; ++j) { acc0[j] = bt0; acc1[j] = bt1; }
        #pragma unroll
        for (int ci = 0; ci < 3; ++ci) {
            #pragma unroll
            for (int dy = 0; dy < 9; ++dy) {
                const float* xr = &sx[ci][r + dy][cg4 * 4];
                float4 xa = *(const float4*)(xr);
                float4 xb = *(const float4*)(xr + 4);
                float4 xc = *(const float4*)(xr + 8);
                float xv[12] = {xa.x, xa.y, xa.z, xa.w,
                                xb.x, xb.y, xb.z, xb.w,
                                xc.x, xc.y, xc.z, xc.w};
                #pragma unroll
                for (int dx = 0; dx < 9; ++dx) {
                    float w0t = W9g[ci * 81 + dy * 9 + dx];
                    float w1t = W9g[243 + ci * 81 + dy * 9 + dx];
                    #pragma unroll
                    for (int j = 0; j < 4; ++j) {
                        acc0[j] += w0t * xv[dx + j];
                        acc1[j] += w1t * xv[dx + j];
                    }
                }
            }
        }
        size_t obase = (size_t)(b * 2) * 102400 + h * 320 + w0c;
        bool edge = (by == 0) | (by == 9) | (bx == 0) | (bx == 9);
        if (!edge) {
            *(float4*)&ini[obase] = make_float4(acc0[0], acc0[1], acc0[2], acc0[3]);
            *(float4*)&ini[obase + 102400] = make_float4(acc1[0], acc1[1], acc1[2], acc1[3]);
        } else {
            bool rring = (h == 0) | (h == 319);
            #pragma unroll
            for (int j = 0; j < 4; ++j) {
                int w = w0c + j;
                if (!rring && w != 0 && w != 319) {
                    ini[obase + j] = acc0[j];
                    ini[obase + 102400 + j] = acc1[j];
                }
            }
        }
        return;
    }
    int witem = (bid - 800) * 4 + (t >> 6);
    int lane = t & 63;
    int b = witem / 1276, j = witem % 1276;
    int h, w;
    if (j < 320)      { h = 0;           w = j; }
    else if (j < 640) { h = 319;         w = j - 320; }
    else if (j < 958) { h = 1 + j - 640; w = 0; }
    else              { h = 1 + j - 958; w = 319; }
    const float* K    = ws + WS_K;
    const float* Beta = ws + WS_BETA;
    float acc0 = 0.f, acc1 = 0.f;
    #pragma unroll
    for (int rep = 0; rep < 3; ++rep) {
        int e = lane + rep * 64;
        if (e < 189) {
            int a = e / 63;    int rem  = e - a * 63;
            int bb = rem / 21; int rem2 = rem - bb * 21;
            int ci = rem2 / 7; int u = rem2 - ci * 7;
            int hh0 = h + a - 1;
            int ww0 = w + bb - 1;
            bool abv = ((unsigned)hh0 < 320u) & ((unsigned)ww0 < 320u);
            if (abv && ci == 0 && u == 0) {
                acc0 += Beta[a * 3 + bb];
                acc1 += Beta[9 + a * 3 + bb];
            }
            int hx = hh0 + u - 3;
            if (abv && (unsigned)hx < 320u) {
                const float* Kc = K + (a * 9 + bb * 3 + ci) * 49 + u * 7;
                const float* xr = x + (b * 3 + ci) * 102400 + hx * 320;
                #pragma unroll
                for (int v = 0; v < 7; ++v) {
                    int wx = ww0 + v - 3;
                    if ((unsigned)wx < 320u) {
                        float xv = xr[wx];
                        acc0 += Kc[v] * xv;
                        acc1 += Kc[1323 + v] * xv;
                    }
                }
            }
        }
    }
    #pragma unroll
    for (int off = 32; off > 0; off >>= 1) {
        acc0 += __shfl_down(acc0, off, 64);
        acc1 += __shfl_down(acc1, off, 64);
    }
    if (lane == 0) {
        size_t pb = (size_t)(b * 2) * 102400 + h * 320 + w;
        ini[pb] = acc0 + bc2[0];
        ini[pb + 102400] = acc1 + bc2[1];
    }
}

__global__ __launch_bounds__(256) void k_trans(const float* __restrict__ ini,
                                               const float* __restrict__ x,
                                               const float* __restrict__ wfm,
                                               const float* __restrict__ bfm,
                                               const float* __restrict__ ws,
                                               ushort* __restrict__ uiL,
                                               ushort* __restrict__ ufL) {
    __shared__ float sM[100 * 50];
    __shared__ float sP[100 * SPS];
    int bc = blockIdx.x;
    int lg = blockIdx.y;
    int zz = blockIdx.z;
    int mode = zz >> 1, pg = zz & 1;
    ushort* outL = mode ? ufL : uiL;
    int t = threadIdx.x;
    const float* Mt = ws + WS_M;
    for (int i = t; i < 5000; i += 256) {
        int r = i / 50, p = i % 50;
        sM[i] = Mt[r * 100 + pg * 50 + p];
    }
    int b = bc >> 1, c = bc & 1;
    int row0 = lg * 20;
    if (mode == 0) {
        for (int e = t; e < 6400; e += 256) {
            int irow = e / 320, col = e % 320;
            int off = (row0 + irow) * 320 + col;
            float val = ini[bc * 102400 + off];
            int li = (irow / 10) * 32 + col / 10;
            int r  = (irow % 10) * 10 + col % 10;
            sP[r * SPS + li] = val;
        }
    } else {
        float wf0 = wfm[c * 3 + 0], wf1 = wfm[c * 3 + 1], wf2 = wfm[c * 3 + 2];
        float bfv = bfm[c];
        for (int e = t; e < 6400; e += 256) {
            int irow = e / 320, col = e % 320;
            int off = (row0 + irow) * 320 + col;
            float val = (bfv + x[(b * 3 + 0) * 102400 + off] * wf0
                             + x[(b * 3 + 1) * 102400 + off] * wf1
                             + x[(b * 3 + 2) * 102400 + off] * wf2) * 0.25f;
            int li = (irow / 10) * 32 + col / 10;
            int r  = (irow % 10) * 10 + col % 10;
            sP[r * SPS + li] = val;
        }
    }
    if (pg == 1) {
        for (int e = t; e < 64 * 7; e += 256) {
            int l = lg * 64 + e / 7, q = e % 7;
            *(uint2*)&outL[((size_t)bc * 1024 + l) * 128 + 100 + q * 4] = make_uint2(0u, 0u);
        }
    }
    __syncthreads();
    if (t < 200) {
        int py = t / 8, lx = t % 8;
        int p0 = py * 2, lo = lx * 8;
        float acc[2][8];
        #pragma unroll
        for (int i = 0; i < 2; ++i)
            #pragma unroll
            for (int j = 0; j < 8; ++j) acc[i][j] = 0.f;
        for (int r = 0; r < 100; ++r) {
            float2 a  = *(const float2*)&sM[r * 50 + p0];
            float4 b0 = *(const float4*)&sP[r * SPS + lo];
            float4 b1 = *(const float4*)&sP[r * SPS + lo + 4];
            float av[2] = {a.x, a.y};
            float bv[8] = {b0.x, b0.y, b0.z, b0.w, b1.x, b1.y, b1.z, b1.w};
            #pragma unroll
            for (int i = 0; i < 2; ++i)
                #pragma unroll
                for (int j = 0; j < 8; ++j)
                    acc[i][j] += av[i] * bv[j];
        }
        int pbase = pg * 50 + p0;
        #pragma unroll
        for (int j = 0; j < 8; ++j) {
            int l = lg * 64 + lo + j;
            unsigned v0 = f2bf(fmaxf(acc[0][j], 0.f));
            unsigned v1 = f2bf(fmaxf(acc[1][j], 0.f));
            *(unsigned*)&outL[((size_t)bc * 1024 + l) * 128 + pbase] = v0 | (v1 << 16);
        }
    }
}

__global__ __launch_bounds__(256) void k_att(const ushort* __restrict__ ui,
                                             const ushort* __restrict__ uf,
                                             float* __restrict__ out) {
    int bc   = blockIdx.z;
    int row0 = blockIdx.y * 128, col0 = blockIdx.x * 128;
    int wave = threadIdx.x >> 6, lane = threadIdx.x & 63;
    int r0 = row0 + (wave >> 1) * 64;
    int c0 = col0 + (wave & 1) * 64;
    int m = lane & 15, quad = lane >> 4;
    const ushort* ub = ui + (size_t)bc * 1024 * 128;
    const ushort* vb = uf + (size_t)bc * 1024 * 128;
    f32x4 acc[4][4];
    #pragma unroll
    for (int i = 0; i < 4; ++i)
        #pragma unroll
        for (int j = 0; j < 4; ++j)
            acc[i][j] = (f32x4){0.f, 0.f, 0.f, 0.f};
    #pragma unroll
    for (int k0 = 0; k0 < 128; k0 += 32) {
        bf16x8 af[4], bfr[4];
        #pragma unroll
        for (int i = 0; i < 4; ++i)
            af[i] = *(const bf16x8*)&ub[(size_t)(r0 + i * 16 + m) * 128 + k0 + quad * 8];
        #pragma unroll
        for (int j = 0; j < 4; ++j)
            bfr[j] = *(const bf16x8*)&vb[(size_t)(c0 + j * 16 + m) * 128 + k0 + quad * 8];
        #pragma unroll
        for (int i = 0; i < 4; ++i)
            #pragma unroll
            for (int j = 0; j < 4; ++j)
                acc[i][j] = __builtin_amdgcn_mfma_f32_16x16x32_bf16(af[i], bfr[j], acc[i][j], 0, 0, 0);
    }
    #pragma unroll
    for (int i = 0; i < 4; ++i) {
        #pragma unroll
        for (int r = 0; r < 4; ++r) {
            int row = r0 + i * 16 + quad * 4 + r;
            float* o = out + ((size_t)bc * 1024 + row) * 1024;
            #pragma unroll
            for (int j = 0; j < 4; ++j)
                o[c0 + j * 16 + m] = acc[i][j][r] * 0.01f;
        }
    }
}

extern "C" void kernel_launch(void* const* d_in, const int* in_sizes, int n_in,
                              void* d_out, int out_size, void* d_ws, size_t ws_size,
                              hipStream_t stream) {
    const float* x       = (const float*)d_in[0];
    const float* w_conv1 = (const float*)d_in[1];
    const float* b_conv1 = (const float*)d_in[2];
    const float* w_conv2 = (const float*)d_in[3];
    const float* b_conv2 = (const float*)d_in[4];
    const float* w_fm    = (const float*)d_in[5];
    const float* b_fm    = (const float*)d_in[6];
    const float* w_lin1  = (const float*)d_in[7];
    const float* w_lin2  = (const float*)d_in[8];
    float* out = (float*)d_out;
    float* ws  = (float*)d_ws;
    ushort* uiL = (ushort*)(ws + WS_UIT);
    ushort* ufL = (ushort*)(ws + WS_UFT);

    // Decide cooperative grid once (host-side queries only; capture-safe).
    static int s_grid = -2;   // -2 uncomputed, -1 cooperative unusable
    if (s_grid == -2) {
        int dev = 0;
        (void)hipGetDevice(&dev);
        hipDeviceProp_t prop;
        int ncu = 256;
        if (hipGetDeviceProperties(&prop, dev) == hipSuccess && prop.multiProcessorCount > 0)
            ncu = prop.multiProcessorCount;
        int nb = 0;
        if (hipOccupancyMaxActiveBlocksPerMultiprocessor(&nb, k_all, 256, 0) != hipSuccess)
            nb = 0;
        if (nb > 3) nb = 3;          // LDS allows 3/CU; don't overcommit
        s_grid = (nb > 0) ? nb * ncu : -1;
    }

    bool done = false;
    if (s_grid > 0) {
        void* args[] = {(void*)&x,
                        (void*)&w_lin1, (void*)&w_lin2,
                        (void*)&w_conv1, (void*)&b_conv1,
                        (void*)&w_conv2, (void*)&b_conv2,
                        (void*)&w_fm, (void*)&b_fm,
                        (void*)&ws, (void*)&out};
        hipError_t e = hipLaunchCooperativeKernel(k_all, dim3(s_grid), dim3(256),
                                                  args, 0u, stream);
        if (e == hipSuccess) done = true;
        else s_grid = -1;   // permanently fall back
    }
    if (!done) {
        k_prep<<<45, 256, 0, stream>>>(w_lin1, w_lin2, w_conv1, b_conv1, w_conv2, b_conv2, ws);
        k_convb<<<3352, 256, 0, stream>>>(x, b_conv2, ws, ws + WS_INI);
        k_trans<<<dim3(16, 16, 4), 256, 0, stream>>>(ws + WS_INI, x, w_fm, b_fm, ws, uiL, ufL);
        k_att<<<dim3(8, 8, 16), 256, 0, stream>>>(uiL, ufL, out);
    }
}

// Round 4
// 261.898 us; speedup vs baseline: 1.2363x; 1.2363x over previous
//
#include <hip/hip_runtime.h>

// Workspace layout (float offsets)
#define WS_M      0        // Mt[r*100+p] = M[p][r] where M = w_lin2 @ w_lin1, 10000 floats
#define WS_K      10000    // K[c][a][b][ci][u][v], 2646 floats
#define WS_BETA   12646    // beta[c][a][b], 18 floats
#define WS_W9     12664    // W9[c][ci][dy][dx], 486 floats
#define WS_BT     13150    // beta_tot[c] (interior combined bias), 2 floats
#define WS_UIT    (16384 + 1638400)      // uiL[bc][l][p128] bf16, 2,097,152 ushorts
#define WS_UFT    (16384 + 2*1638400)    // ufL[bc][l][p128] bf16

typedef short bf16x8 __attribute__((ext_vector_type(8)));
typedef float f32x4  __attribute__((ext_vector_type(4)));

__device__ inline ushort f2bf(float f) {   // round-to-nearest-even
    unsigned u = __float_as_uint(f);
    unsigned r = (u + 0x7fffu + ((u >> 16) & 1u)) >> 16;
    return (ushort)r;
}

// ---------------------------------------------------------------------------
// Prep (unchanged from the 170us version). blocks 0..39: Mt. blocks 40..42: K
// (block 40 also Beta+Bt). blocks 43..44: W9 from raw weights.
__global__ __launch_bounds__(256) void k_prep(const float* __restrict__ wl1,
                                              const float* __restrict__ wl2,
                                              const float* __restrict__ wc1,
                                              const float* __restrict__ bc1,
                                              const float* __restrict__ wc2,
                                              const float* __restrict__ bc2,
                                              float* __restrict__ ws) {
    int blk = blockIdx.x;
    int t = threadIdx.x;
    if (blk < 40) {
        int idx = blk * 256 + t;
        if (idx < 10000) {
            int p = idx / 100, r = idx % 100;
            float s = 0.f;
            for (int q = 0; q < 200; ++q)
                s += wl2[p * 200 + q] * wl1[q * 100 + r];
            ws[WS_M + r * 100 + p] = s;
        }
        return;
    }
    __shared__ float swc1[9408];   // 64*3*49
    __shared__ float swc2[1152];   // 2*64*9
    __shared__ float sBeta[18];
    for (int i = t; i < 9408; i += 256) swc1[i] = wc1[i];
    for (int i = t; i < 1152; i += 256) swc2[i] = wc2[i];
    __syncthreads();
    if (blk < 43) {
        int base = (blk - 40) * 882;
        for (int ii = t; ii < 882; ii += 256) {
            int idx = base + ii;
            int v = idx % 7; int t1 = idx / 7;
            int u = t1 % 7;  int t2 = t1 / 7;
            int ci = t2 % 3; int t3 = t2 / 3;
            int b = t3 % 3;  int t4 = t3 / 3;
            int a = t4 % 3;  int c = t4 / 3;
            float s = 0.f;
            for (int c64 = 0; c64 < 64; ++c64)
                s += swc2[((c * 64 + c64) * 3 + a) * 3 + b] *
                     swc1[((c64 * 3 + ci) * 7 + u) * 7 + v];
            ws[WS_K + idx] = s;
        }
        if (blk == 40) {
            if (t < 18) {
                int b = t % 3; int a = (t / 3) % 3; int c = t / 9;
                float s = 0.f;
                for (int c64 = 0; c64 < 64; ++c64)
                    s += swc2[((c * 64 + c64) * 3 + a) * 3 + b] * bc1[c64];
                sBeta[t] = s; ws[WS_BETA + t] = s;
            }
            __syncthreads();
            if (t < 2) {
                float s = bc2[t];
                for (int j2 = 0; j2 < 9; ++j2) s += sBeta[t * 9 + j2];
                ws[WS_BT + t] = s;
            }
        }
    } else {
        int idx = (blk - 43) * 243 + t;
        if (t < 243) {
            int dx = idx % 9; int t1 = idx / 9;
            int dy = t1 % 9;  int t2 = t1 / 9;
            int ci = t2 % 3;  int c = t2 / 3;
            float s = 0.f;
            for (int a = 0; a < 3; ++a) {
                int u = dy - a; if (u < 0 || u > 6) continue;
                for (int b = 0; b < 3; ++b) {
                    int v = dx - b; if (v < 0 || v > 6) continue;
                    for (int c64 = 0; c64 < 64; ++c64)
                        s += swc2[((c * 64 + c64) * 3 + a) * 3 + b] *
                             swc1[((c64 * 3 + ci) * 7 + u) * 7 + v];
                }
            }
            ws[WS_W9 + idx] = s;   // layout c*243 + ci*81 + dy*9 + dx
        }
    }
}

// ---------------------------------------------------------------------------
// Fused conv + exact border + trans(both modes). 40x40 tile = 4x4 patches.
// Grid (8,8,8). ini is never materialized: patches live in LDS only.
//   phase 1: W9 composite conv (200 thr x 8 px x 2 ch), write sP[2][100][16]
//   phase 2: edge blocks overwrite ring px with exact K/Beta path (taps from sx)
//   phase 3: trans -> uiL (100 lanes/plane own one p-col each; acc[16] over l)
//   phase 4: fea = 1x1 conv of x (from sx) -> sP ; phase 5: trans -> ufL
__global__ __launch_bounds__(256) void k_fuse(const float* __restrict__ x,
                                              const float* __restrict__ bc2,
                                              const float* __restrict__ wfm,
                                              const float* __restrict__ bfm,
                                              const float* __restrict__ ws,
                                              ushort* __restrict__ uiL,
                                              ushort* __restrict__ ufL) {
    __shared__ float sx[3][48][52];    // halo tile, stride 52: conflict-free f4
    __shared__ float sP[2][100][20];   // patches [ch][r][li16+pad4]
    const int bx = blockIdx.x, by = blockIdx.y, b = blockIdx.z;
    const int t = threadIdx.x;
    const float* Mt   = ws + WS_M;
    const float* Kw   = ws + WS_K;
    const float* Beta = ws + WS_BETA;
    const float* W9   = ws + WS_W9;
    const float* Bt   = ws + WS_BT;
    const int gh0 = by * 40, gw0 = bx * 40;

    // ---- stage x halo (zero-padded)
    for (int idx = t; idx < 3 * 48 * 48; idx += 256) {
        int ci = idx / 2304; int rem = idx - ci * 2304;
        int rr = rem / 48, cc = rem - rr * 48;
        int gh = gh0 - 4 + rr, gw = gw0 - 4 + cc;
        float v = 0.f;
        if ((unsigned)gh < 320u && (unsigned)gw < 320u)
            v = x[(b * 3 + ci) * 102400 + gh * 320 + gw];
        sx[ci][rr][cc] = v;
    }
    __syncthreads();

    // ---- phase 1: interior-composite 9x9 conv, 200 threads x 8 px x 2 ch
    const int lh = t / 5, lw0 = (t % 5) * 8;   // valid for t<200
    if (t < 200) {
        float acc0[8], acc1[8];
        float bt0 = Bt[0], bt1 = Bt[1];
        #pragma unroll
        for (int j = 0; j < 8; ++j) { acc0[j] = bt0; acc1[j] = bt1; }
        #pragma unroll
        for (int ci = 0; ci < 3; ++ci) {
            #pragma unroll
            for (int dy = 0; dy < 9; ++dy) {
                const float* xr = &sx[ci][lh + dy][lw0];
                float4 xa = *(const float4*)(xr);
                float4 xb = *(const float4*)(xr + 4);
                float4 xc = *(const float4*)(xr + 8);
                float4 xd = *(const float4*)(xr + 12);
                float xv[16] = {xa.x, xa.y, xa.z, xa.w, xb.x, xb.y, xb.z, xb.w,
                                xc.x, xc.y, xc.z, xc.w, xd.x, xd.y, xd.z, xd.w};
                #pragma unroll
                for (int dx = 0; dx < 9; ++dx) {
                    float w0t = W9[ci * 81 + dy * 9 + dx];
                    float w1t = W9[243 + ci * 81 + dy * 9 + dx];
                    #pragma unroll
                    for (int j = 0; j < 8; ++j) {
                        acc0[j] += w0t * xv[dx + j];
                        acc1[j] += w1t * xv[dx + j];
                    }
                }
            }
        }
        #pragma unroll
        for (int j = 0; j < 8; ++j) {
            int lw = lw0 + j;
            int li = (lh / 10) * 4 + lw / 10;
            int r  = (lh % 10) * 10 + lw % 10;
            sP[0][r][li] = acc0[j];
            sP[1][r][li] = acc1[j];
        }
    }
    __syncthreads();

    // ---- phase 2: exact ring overwrite (edge blocks). Taps reach +-4 of the
    // ring pixel -> entirely inside the staged sx halo (zero pad = conv7 pad).
    // Only (a,b) validity matters (conv3's padding pads y, killing K AND beta).
    bool edgeblk = (by == 0) | (by == 7) | (bx == 0) | (bx == 7);
    if (edgeblk) {
        float b20 = bc2[0], b21 = bc2[1];
        for (int e = t; e < 1600; e += 256) {
            int elh = e / 40, elw = e % 40;
            int h = gh0 + elh, w = gw0 + elw;
            if (h == 0 || h == 319 || w == 0 || w == 319) {
                float a0 = b20, a1 = b21;
                for (int a = 0; a < 3; ++a) {
                    int hh = h + a - 1;
                    if ((unsigned)hh >= 320u) continue;
                    for (int bb = 0; bb < 3; ++bb) {
                        int wwp = w + bb - 1;
                        if ((unsigned)wwp >= 320u) continue;
                        a0 += Beta[a * 3 + bb];
                        a1 += Beta[9 + a * 3 + bb];
                        for (int ci = 0; ci < 3; ++ci) {
                            const float* Kc = Kw + ((a * 3 + bb) * 3 + ci) * 49;
                            #pragma unroll
                            for (int u = 0; u < 7; ++u) {
                                #pragma unroll
                                for (int v = 0; v < 7; ++v) {
                                    float xv = sx[ci][elh + a + u][elw + bb + v];
                                    a0 += Kc[u * 7 + v] * xv;
                                    a1 += Kc[1323 + u * 7 + v] * xv;
                                }
                            }
                        }
                    }
                }
                int li = (elh / 10) * 4 + elw / 10;
                int r  = (elh % 10) * 10 + elw % 10;
                sP[0][r][li] = a0;
                sP[1][r][li] = a1;
            }
        }
    }
    __syncthreads();

    // ---- trans: lanes 0..99 plane 0, 100..199 plane 1; each owns column p.
    // acc[16] = the tile's 16 patches. sP reads are wave-broadcast. Lanes
    // 200..255 write the p-pad [100,128) zeros.
    auto trans = [&](ushort* outL) {
        if (t < 200) {
            int plane = (t >= 100) ? 1 : 0;
            int p = t - plane * 100;
            int bc = b * 2 + plane;
            float acc[16];
            #pragma unroll
            for (int k = 0; k < 16; ++k) acc[k] = 0.f;
            for (int r = 0; r < 100; ++r) {
                float m = Mt[r * 100 + p];
                f32x4 s0 = *(const f32x4*)&sP[plane][r][0];
                f32x4 s1 = *(const f32x4*)&sP[plane][r][4];
                f32x4 s2 = *(const f32x4*)&sP[plane][r][8];
                f32x4 s3 = *(const f32x4*)&sP[plane][r][12];
                #pragma unroll
                for (int k = 0; k < 4; ++k) acc[k]      += m * s0[k];
                #pragma unroll
                for (int k = 0; k < 4; ++k) acc[4 + k]  += m * s1[k];
                #pragma unroll
                for (int k = 0; k < 4; ++k) acc[8 + k]  += m * s2[k];
                #pragma unroll
                for (int k = 0; k < 4; ++k) acc[12 + k] += m * s3[k];
            }
            #pragma unroll
            for (int k = 0; k < 16; ++k) {
                int l = (by * 4 + (k >> 2)) * 32 + bx * 4 + (k & 3);
                outL[((size_t)bc * 1024 + l) * 128 + p] = f2bf(fmaxf(acc[k], 0.f));
            }
        } else {
            for (int task = t - 200; task < 224; task += 56) {
                int plane = task / 112; int rem = task % 112;
                int k = rem / 7, q = rem % 7;
                int bc = b * 2 + plane;
                int l = (by * 4 + (k >> 2)) * 32 + bx * 4 + (k & 3);
                *(uint2*)&outL[((size_t)bc * 1024 + l) * 128 + 100 + q * 4] =
                    make_uint2(0u, 0u);
            }
        }
    };

    trans(uiL);            // ---- phase 3: U_i
    __syncthreads();       // sP reads done before fea overwrites

    // ---- phase 4: fea = (b_fm + x . w_fm)/4 from staged x
    if (t < 200) {
        float wf00 = wfm[0], wf01 = wfm[1], wf02 = wfm[2];
        float wf10 = wfm[3], wf11 = wfm[4], wf12 = wfm[5];
        float bf0 = bfm[0], bf1 = bfm[1];
        #pragma unroll
        for (int j = 0; j < 8; ++j) {
            int lw = lw0 + j;
            float s0 = sx[0][4 + lh][4 + lw];
            float s1 = sx[1][4 + lh][4 + lw];
            float s2 = sx[2][4 + lh][4 + lw];
            float v0 = (bf0 + s0 * wf00 + s1 * wf01 + s2 * wf02) * 0.25f;
            float v1 = (bf1 + s0 * wf10 + s1 * wf11 + s2 * wf12) * 0.25f;
            int li = (lh / 10) * 4 + lw / 10;
            int r  = (lh % 10) * 10 + lw % 10;
            sP[0][r][li] = v0;
            sP[1][r][li] = v1;
        }
    }
    __syncthreads();

    trans(ufL);            // ---- phase 5: U_f
}

// ---------------------------------------------------------------------------
// att[bc][l][m] = (1/100) * sum_p ui[l][p]*uf[m][p], bf16 MFMA 16x16x32.
// 128x128 tile/block, 4 waves 2x2, each wave 64x64 = 4x4 mfma tiles.
__global__ __launch_bounds__(256) void k_att(const ushort* __restrict__ ui,
                                             const ushort* __restrict__ uf,
                                             float* __restrict__ out) {
    int bc   = blockIdx.z;
    int row0 = blockIdx.y * 128, col0 = blockIdx.x * 128;
    int wave = threadIdx.x >> 6, lane = threadIdx.x & 63;
    int r0 = row0 + (wave >> 1) * 64;
    int c0 = col0 + (wave & 1) * 64;
    int m = lane & 15, quad = lane >> 4;
    const ushort* ub = ui + (size_t)bc * 1024 * 128;
    const ushort* vb = uf + (size_t)bc * 1024 * 128;
    f32x4 acc[4][4];
    #pragma unroll
    for (int i = 0; i < 4; ++i)
        #pragma unroll
        for (int j = 0; j < 4; ++j)
            acc[i][j] = (f32x4){0.f, 0.f, 0.f, 0.f};
    #pragma unroll
    for (int k0 = 0; k0 < 128; k0 += 32) {
        bf16x8 af[4], bfr[4];
        #pragma unroll
        for (int i = 0; i < 4; ++i)
            af[i] = *(const bf16x8*)&ub[(size_t)(r0 + i * 16 + m) * 128 + k0 + quad * 8];
        #pragma unroll
        for (int j = 0; j < 4; ++j)
            bfr[j] = *(const bf16x8*)&vb[(size_t)(c0 + j * 16 + m) * 128 + k0 + quad * 8];
        #pragma unroll
        for (int i = 0; i < 4; ++i)
            #pragma unroll
            for (int j = 0; j < 4; ++j)
                acc[i][j] = __builtin_amdgcn_mfma_f32_16x16x32_bf16(af[i], bfr[j], acc[i][j], 0, 0, 0);
    }
    // C/D: col = lane&15, row = quad*4 + reg (m89/m91-verified)
    #pragma unroll
    for (int i = 0; i < 4; ++i) {
        #pragma unroll
        for (int r = 0; r < 4; ++r) {
            int row = r0 + i * 16 + quad * 4 + r;
            float* o = out + ((size_t)bc * 1024 + row) * 1024;
            #pragma unroll
            for (int j = 0; j < 4; ++j)
                o[c0 + j * 16 + m] = acc[i][j][r] * 0.01f;
        }
    }
}

extern "C" void kernel_launch(void* const* d_in, const int* in_sizes, int n_in,
                              void* d_out, int out_size, void* d_ws, size_t ws_size,
                              hipStream_t stream) {
    const float* x       = (const float*)d_in[0];
    const float* w_conv1 = (const float*)d_in[1];
    const float* b_conv1 = (const float*)d_in[2];
    const float* w_conv2 = (const float*)d_in[3];
    const float* b_conv2 = (const float*)d_in[4];
    const float* w_fm    = (const float*)d_in[5];
    const float* b_fm    = (const float*)d_in[6];
    const float* w_lin1  = (const float*)d_in[7];
    const float* w_lin2  = (const float*)d_in[8];
    float* out = (float*)d_out;
    float* ws  = (float*)d_ws;
    ushort* uiL = (ushort*)(ws + WS_UIT);
    ushort* ufL = (ushort*)(ws + WS_UFT);

    k_prep<<<45, 256, 0, stream>>>(w_lin1, w_lin2, w_conv1, b_conv1, w_conv2, b_conv2, ws);
    k_fuse<<<dim3(8, 8, 8), 256, 0, stream>>>(x, b_conv2, w_fm, b_fm, ws, uiL, ufL);
    k_att<<<dim3(8, 8, 16), 256, 0, stream>>>(uiL, ufL, out);
}

// Round 5
// 211.997 us; speedup vs baseline: 1.5272x; 1.2354x over previous
//
#include <hip/hip_runtime.h>

// Workspace layout (float offsets)
#define WS_M      0        // Mt[r*100+p] = M[p][r] where M = w_lin2 @ w_lin1, 10000 floats
#define WS_K      10000    // K[c][a][b][ci][u][v], 2646 floats
#define WS_BETA   12646    // beta[c][a][b], 18 floats
#define WS_W9     12664    // W9[c][ci][dy][dx], 486 floats
#define WS_BT     13150    // beta_tot[c] (interior combined bias), 2 floats
#define WS_UIT    (16384 + 1638400)      // uiL[bc][l][p128] bf16, 2,097,152 ushorts
#define WS_UFT    (16384 + 2*1638400)    // ufL[bc][l][p128] bf16

typedef short bf16x8 __attribute__((ext_vector_type(8)));
typedef float f32x4  __attribute__((ext_vector_type(4)));

__device__ inline ushort f2bf(float f) {   // round-to-nearest-even
    unsigned u = __float_as_uint(f);
    unsigned r = (u + 0x7fffu + ((u >> 16) & 1u)) >> 16;
    return (ushort)r;
}

// ---------------------------------------------------------------------------
// Prep. blocks 0..39: Mt. blocks 40..42: K (block 40 also Beta+Bt).
// blocks 43..44: W9 from raw weights.
__global__ __launch_bounds__(256) void k_prep(const float* __restrict__ wl1,
                                              const float* __restrict__ wl2,
                                              const float* __restrict__ wc1,
                                              const float* __restrict__ bc1,
                                              const float* __restrict__ wc2,
                                              const float* __restrict__ bc2,
                                              float* __restrict__ ws) {
    int blk = blockIdx.x;
    int t = threadIdx.x;
    if (blk < 40) {
        int idx = blk * 256 + t;
        if (idx < 10000) {
            int p = idx / 100, r = idx % 100;
            float s = 0.f;
            for (int q = 0; q < 200; ++q)
                s += wl2[p * 200 + q] * wl1[q * 100 + r];
            ws[WS_M + r * 100 + p] = s;
        }
        return;
    }
    __shared__ float swc1[9408];   // 64*3*49
    __shared__ float swc2[1152];   // 2*64*9
    __shared__ float sBeta[18];
    for (int i = t; i < 9408; i += 256) swc1[i] = wc1[i];
    for (int i = t; i < 1152; i += 256) swc2[i] = wc2[i];
    __syncthreads();
    if (blk < 43) {
        int base = (blk - 40) * 882;
        for (int ii = t; ii < 882; ii += 256) {
            int idx = base + ii;
            int v = idx % 7; int t1 = idx / 7;
            int u = t1 % 7;  int t2 = t1 / 7;
            int ci = t2 % 3; int t3 = t2 / 3;
            int b = t3 % 3;  int t4 = t3 / 3;
            int a = t4 % 3;  int c = t4 / 3;
            float s = 0.f;
            for (int c64 = 0; c64 < 64; ++c64)
                s += swc2[((c * 64 + c64) * 3 + a) * 3 + b] *
                     swc1[((c64 * 3 + ci) * 7 + u) * 7 + v];
            ws[WS_K + idx] = s;
        }
        if (blk == 40) {
            if (t < 18) {
                int b = t % 3; int a = (t / 3) % 3; int c = t / 9;
                float s = 0.f;
                for (int c64 = 0; c64 < 64; ++c64)
                    s += swc2[((c * 64 + c64) * 3 + a) * 3 + b] * bc1[c64];
                sBeta[t] = s; ws[WS_BETA + t] = s;
            }
            __syncthreads();
            if (t < 2) {
                float s = bc2[t];
                for (int j2 = 0; j2 < 9; ++j2) s += sBeta[t * 9 + j2];
                ws[WS_BT + t] = s;
            }
        }
    } else {
        int idx = (blk - 43) * 243 + t;
        if (t < 243) {
            int dx = idx % 9; int t1 = idx / 9;
            int dy = t1 % 9;  int t2 = t1 / 9;
            int ci = t2 % 3;  int c = t2 / 3;
            float s = 0.f;
            for (int a = 0; a < 3; ++a) {
                int u = dy - a; if (u < 0 || u > 6) continue;
                for (int b = 0; b < 3; ++b) {
                    int v = dx - b; if (v < 0 || v > 6) continue;
                    for (int c64 = 0; c64 < 64; ++c64)
                        s += swc2[((c * 64 + c64) * 3 + a) * 3 + b] *
                             swc1[((c64 * 3 + ci) * 7 + u) * 7 + v];
                }
            }
            ws[WS_W9 + idx] = s;   // layout c*243 + ci*81 + dy*9 + dx
        }
    }
}

// ---------------------------------------------------------------------------
// Fused conv + border-correction + trans(both modes). 20x20 tile = 2x2 patches.
// Grid (16,16,8) = 2048 blocks = 8/CU. LDS 18.5 KB -> 8 blocks/CU possible.
//   phase 1: W9 composite conv (200 thr x 2 px x 2 ch) -> sP[2][100][4]
//   phase 2: ring px exact fix: subtract invalid-(a,b) terms (3 edge / 5 corner)
//   phase 3: trans -> uiL; phase 4: fea from sx -> sP; phase 5: trans -> ufL
__global__ __launch_bounds__(256, 6) void k_fuse(const float* __restrict__ x,
                                                 const float* __restrict__ wfm,
                                                 const float* __restrict__ bfm,
                                                 const float* __restrict__ ws,
                                                 ushort* __restrict__ uiL,
                                                 ushort* __restrict__ ufL) {
    __shared__ float sx[3][28][36];    // halo tile; stride 36: 16B-aligned rows,
                                       // banks rotate by 4 per row
    __shared__ float sP[2][100][8];    // patches [ch][r][li4+pad4]; rows 32B
    const int bx = blockIdx.x, by = blockIdx.y, b = blockIdx.z;
    const int t = threadIdx.x;
    const float* Mt   = ws + WS_M;
    const float* Kw   = ws + WS_K;
    const float* Beta = ws + WS_BETA;
    const float* W9   = ws + WS_W9;
    const float* Bt   = ws + WS_BT;
    const int gh0 = by * 20, gw0 = bx * 20;

    // ---- stage x halo (zero-padded at image border)
    for (int idx = t; idx < 3 * 28 * 28; idx += 256) {
        int ci = idx / 784; int rem = idx - ci * 784;
        int rr = rem / 28, cc = rem - rr * 28;
        int gh = gh0 - 4 + rr, gw = gw0 - 4 + cc;
        float v = 0.f;
        if ((unsigned)gh < 320u && (unsigned)gw < 320u)
            v = x[(b * 3 + ci) * 102400 + gh * 320 + gw];
        sx[ci][rr][cc] = v;
    }
    __syncthreads();

    // ---- phase 1: interior-composite 9x9 conv; 200 thr x 2 px x 2 ch
    const int lh = t / 10, lw0 = (t % 10) * 2;   // valid for t<200
    if (t < 200) {
        float acc0[2], acc1[2];
        float bt0 = Bt[0], bt1 = Bt[1];
        acc0[0] = bt0; acc0[1] = bt0; acc1[0] = bt1; acc1[1] = bt1;
        #pragma unroll
        for (int ci = 0; ci < 3; ++ci) {
            #pragma unroll
            for (int dy = 0; dy < 9; ++dy) {
                const float* xr = &sx[ci][lh + dy][lw0];
                float2 y0 = *(const float2*)(xr);
                float2 y1 = *(const float2*)(xr + 2);
                float2 y2 = *(const float2*)(xr + 4);
                float2 y3 = *(const float2*)(xr + 6);
                float2 y4 = *(const float2*)(xr + 8);
                float xv[10] = {y0.x, y0.y, y1.x, y1.y, y2.x,
                                y2.y, y3.x, y3.y, y4.x, y4.y};
                #pragma unroll
                for (int dx = 0; dx < 9; ++dx) {
                    float w0t = W9[ci * 81 + dy * 9 + dx];
                    float w1t = W9[243 + ci * 81 + dy * 9 + dx];
                    acc0[0] += w0t * xv[dx];
                    acc0[1] += w0t * xv[dx + 1];
                    acc1[0] += w1t * xv[dx];
                    acc1[1] += w1t * xv[dx + 1];
                }
            }
        }
        #pragma unroll
        for (int j = 0; j < 2; ++j) {
            int lw = lw0 + j;
            int li = (lh / 10) * 2 + lw / 10;
            int r  = (lh % 10) * 10 + lw % 10;
            sP[0][r][li] = acc0[j];
            sP[1][r][li] = acc1[j];
        }
    }
    __syncthreads();

    // ---- phase 2: ring correction. exact = phase1 - sum_{invalid(a,bb)}
    // [beta_ab + K_ab (*) x_pad]; taps stay within the staged halo.
    bool edgeblk = (by == 0) | (by == 15) | (bx == 0) | (bx == 15);
    if (edgeblk) {
        for (int e = t; e < 400; e += 256) {
            int elh = e / 20, elw = e % 20;
            int h = gh0 + elh, w = gw0 + elw;
            if (h == 0 || h == 319 || w == 0 || w == 319) {
                float c0 = 0.f, c1 = 0.f;
                for (int a = 0; a < 3; ++a) {
                    int hh = h + a - 1;
                    for (int bb = 0; bb < 3; ++bb) {
                        int wwp = w + bb - 1;
                        bool invalid = ((unsigned)hh >= 320u) | ((unsigned)wwp >= 320u);
                        if (invalid) {
                            c0 += Beta[a * 3 + bb];
                            c1 += Beta[9 + a * 3 + bb];
                            for (int ci = 0; ci < 3; ++ci) {
                                const float* Kc = Kw + ((a * 3 + bb) * 3 + ci) * 49;
                                #pragma unroll
                                for (int u = 0; u < 7; ++u) {
                                    #pragma unroll
                                    for (int v = 0; v < 7; ++v) {
                                        float xv = sx[ci][elh + a + u][elw + bb + v];
                                        c0 += Kc[u * 7 + v] * xv;
                                        c1 += Kc[1323 + u * 7 + v] * xv;
                                    }
                                }
                            }
                        }
                    }
                }
                int li = (elh / 10) * 2 + elw / 10;
                int r  = (elh % 10) * 10 + elw % 10;
                sP[0][r][li] -= c0;
                sP[1][r][li] -= c1;
            }
        }
    }
    __syncthreads();

    // ---- trans: lanes 0..199 own (plane = t/100, p = t%100); acc[4] = the
    // tile's 4 patches; sP reads wave-broadcast; Mt reads coalesced in p.
    // Lanes 200..255 (56 = 2 planes x 4 l x 7 quads) write the p-pad zeros.
    auto trans = [&](ushort* outL) {
        if (t < 200) {
            int plane = (t >= 100) ? 1 : 0;
            int p = t - plane * 100;
            int bc = b * 2 + plane;
            float acc[4] = {0.f, 0.f, 0.f, 0.f};
            for (int r = 0; r < 100; ++r) {
                float m = Mt[r * 100 + p];
                f32x4 s = *(const f32x4*)&sP[plane][r][0];
                #pragma unroll
                for (int k = 0; k < 4; ++k) acc[k] += m * s[k];
            }
            #pragma unroll
            for (int k = 0; k < 4; ++k) {
                int l = (by * 2 + (k >> 1)) * 32 + bx * 2 + (k & 1);
                outL[((size_t)bc * 1024 + l) * 128 + p] = f2bf(fmaxf(acc[k], 0.f));
            }
        } else if (t < 256) {
            int task = t - 200;
            if (task < 56) {
                int plane = task / 28; int rem = task % 28;
                int k = rem / 7, q = rem % 7;
                int bc = b * 2 + plane;
                int l = (by * 2 + (k >> 1)) * 32 + bx * 2 + (k & 1);
                *(uint2*)&outL[((size_t)bc * 1024 + l) * 128 + 100 + q * 4] =
                    make_uint2(0u, 0u);
            }
        }
    };

    trans(uiL);            // ---- phase 3: U_i
    __syncthreads();       // sP reads done before fea overwrites

    // ---- phase 4: fea = (b_fm + x . w_fm)/4 from staged x
    if (t < 200) {
        float wf00 = wfm[0], wf01 = wfm[1], wf02 = wfm[2];
        float wf10 = wfm[3], wf11 = wfm[4], wf12 = wfm[5];
        float bf0 = bfm[0], bf1 = bfm[1];
        #pragma unroll
        for (int j = 0; j < 2; ++j) {
            int lw = lw0 + j;
            float s0 = sx[0][4 + lh][4 + lw];
            float s1 = sx[1][4 + lh][4 + lw];
            float s2 = sx[2][4 + lh][4 + lw];
            float v0 = (bf0 + s0 * wf00 + s1 * wf01 + s2 * wf02) * 0.25f;
            float v1 = (bf1 + s0 * wf10 + s1 * wf11 + s2 * wf12) * 0.25f;
            int li = (lh / 10) * 2 + lw / 10;
            int r  = (lh % 10) * 10 + lw % 10;
            sP[0][r][li] = v0;
            sP[1][r][li] = v1;
        }
    }
    __syncthreads();

    trans(ufL);            // ---- phase 5: U_f
}

// ---------------------------------------------------------------------------
// att[bc][l][m] = (1/100) * sum_p ui[l][p]*uf[m][p], bf16 MFMA 16x16x32.
// 128x128 tile/block, 4 waves 2x2, each wave 64x64 = 4x4 mfma tiles.
__global__ __launch_bounds__(256) void k_att(const ushort* __restrict__ ui,
                                             const ushort* __restrict__ uf,
                                             float* __restrict__ out) {
    int bc   = blockIdx.z;
    int row0 = blockIdx.y * 128, col0 = blockIdx.x * 128;
    int wave = threadIdx.x >> 6, lane = threadIdx.x & 63;
    int r0 = row0 + (wave >> 1) * 64;
    int c0 = col0 + (wave & 1) * 64;
    int m = lane & 15, quad = lane >> 4;
    const ushort* ub = ui + (size_t)bc * 1024 * 128;
    const ushort* vb = uf + (size_t)bc * 1024 * 128;
    f32x4 acc[4][4];
    #pragma unroll
    for (int i = 0; i < 4; ++i)
        #pragma unroll
        for (int j = 0; j < 4; ++j)
            acc[i][j] = (f32x4){0.f, 0.f, 0.f, 0.f};
    #pragma unroll
    for (int k0 = 0; k0 < 128; k0 += 32) {
        bf16x8 af[4], bfr[4];
        #pragma unroll
        for (int i = 0; i < 4; ++i)
            af[i] = *(const bf16x8*)&ub[(size_t)(r0 + i * 16 + m) * 128 + k0 + quad * 8];
        #pragma unroll
        for (int j = 0; j < 4; ++j)
            bfr[j] = *(const bf16x8*)&vb[(size_t)(c0 + j * 16 + m) * 128 + k0 + quad * 8];
        #pragma unroll
        for (int i = 0; i < 4; ++i)
            #pragma unroll
            for (int j = 0; j < 4; ++j)
                acc[i][j] = __builtin_amdgcn_mfma_f32_16x16x32_bf16(af[i], bfr[j], acc[i][j], 0, 0, 0);
    }
    // C/D: col = lane&15, row = quad*4 + reg (m89/m91-verified)
    #pragma unroll
    for (int i = 0; i < 4; ++i) {
        #pragma unroll
        for (int r = 0; r < 4; ++r) {
            int row = r0 + i * 16 + quad * 4 + r;
            float* o = out + ((size_t)bc * 1024 + row) * 1024;
            #pragma unroll
            for (int j = 0; j < 4; ++j)
                o[c0 + j * 16 + m] = acc[i][j][r] * 0.01f;
        }
    }
}

extern "C" void kernel_launch(void* const* d_in, const int* in_sizes, int n_in,
                              void* d_out, int out_size, void* d_ws, size_t ws_size,
                              hipStream_t stream) {
    const float* x       = (const float*)d_in[0];
    const float* w_conv1 = (const float*)d_in[1];
    const float* b_conv1 = (const float*)d_in[2];
    const float* w_conv2 = (const float*)d_in[3];
    const float* b_conv2 = (const float*)d_in[4];
    const float* w_fm    = (const float*)d_in[5];
    const float* b_fm    = (const float*)d_in[6];
    const float* w_lin1  = (const float*)d_in[7];
    const float* w_lin2  = (const float*)d_in[8];
    float* out = (float*)d_out;
    float* ws  = (float*)d_ws;
    ushort* uiL = (ushort*)(ws + WS_UIT);
    ushort* ufL = (ushort*)(ws + WS_UFT);

    k_prep<<<45, 256, 0, stream>>>(w_lin1, w_lin2, w_conv1, b_conv1, w_conv2, b_conv2, ws);
    k_fuse<<<dim3(16, 16, 8), 256, 0, stream>>>(x, w_fm, b_fm, ws, uiL, ufL);
    k_att<<<dim3(8, 8, 16), 256, 0, stream>>>(uiL, ufL, out);
}

// Round 6
// 204.780 us; speedup vs baseline: 1.5811x; 1.0352x over previous
//
#include <hip/hip_runtime.h>

// Workspace layout (float offsets)
#define WS_M      0        // Mt[r*100+p] = M[p][r] where M = w_lin2 @ w_lin1, 10000 floats
#define WS_K      10000    // K[c][a][b][ci][u][v], 2646 floats
#define WS_BETA   12646    // beta[c][a][b], 18 floats
#define WS_W9     12664    // W9[c][ci][dy][dx], 486 floats
#define WS_BT     13150    // beta_tot[c] (interior combined bias), 2 floats
#define WS_UIT    (16384 + 1638400)      // uiL[bc][l][p128] bf16, 2,097,152 ushorts
#define WS_UFT    (16384 + 2*1638400)    // ufL[bc][l][p128] bf16

typedef short bf16x8 __attribute__((ext_vector_type(8)));
typedef float f32x4  __attribute__((ext_vector_type(4)));

__device__ inline ushort f2bf(float f) {   // round-to-nearest-even
    unsigned u = __float_as_uint(f);
    unsigned r = (u + 0x7fffu + ((u >> 16) & 1u)) >> 16;
    return (ushort)r;
}

// ---------------------------------------------------------------------------
// Prep. blocks 0..39: Mt. blocks 40..42: K (block 40 also Beta+Bt).
// blocks 43..44: W9 from raw weights.
__global__ __launch_bounds__(256) void k_prep(const float* __restrict__ wl1,
                                              const float* __restrict__ wl2,
                                              const float* __restrict__ wc1,
                                              const float* __restrict__ bc1,
                                              const float* __restrict__ wc2,
                                              const float* __restrict__ bc2,
                                              float* __restrict__ ws) {
    int blk = blockIdx.x;
    int t = threadIdx.x;
    if (blk < 40) {
        int idx = blk * 256 + t;
        if (idx < 10000) {
            int p = idx / 100, r = idx % 100;
            float s = 0.f;
            for (int q = 0; q < 200; ++q)
                s += wl2[p * 200 + q] * wl1[q * 100 + r];
            ws[WS_M + r * 100 + p] = s;
        }
        return;
    }
    __shared__ float swc1[9408];   // 64*3*49
    __shared__ float swc2[1152];   // 2*64*9
    __shared__ float sBeta[18];
    for (int i = t; i < 9408; i += 256) swc1[i] = wc1[i];
    for (int i = t; i < 1152; i += 256) swc2[i] = wc2[i];
    __syncthreads();
    if (blk < 43) {
        int base = (blk - 40) * 882;
        for (int ii = t; ii < 882; ii += 256) {
            int idx = base + ii;
            int v = idx % 7; int t1 = idx / 7;
            int u = t1 % 7;  int t2 = t1 / 7;
            int ci = t2 % 3; int t3 = t2 / 3;
            int b = t3 % 3;  int t4 = t3 / 3;
            int a = t4 % 3;  int c = t4 / 3;
            float s = 0.f;
            for (int c64 = 0; c64 < 64; ++c64)
                s += swc2[((c * 64 + c64) * 3 + a) * 3 + b] *
                     swc1[((c64 * 3 + ci) * 7 + u) * 7 + v];
            ws[WS_K + idx] = s;
        }
        if (blk == 40) {
            if (t < 18) {
                int b = t % 3; int a = (t / 3) % 3; int c = t / 9;
                float s = 0.f;
                for (int c64 = 0; c64 < 64; ++c64)
                    s += swc2[((c * 64 + c64) * 3 + a) * 3 + b] * bc1[c64];
                sBeta[t] = s; ws[WS_BETA + t] = s;
            }
            __syncthreads();
            if (t < 2) {
                float s = bc2[t];
                for (int j2 = 0; j2 < 9; ++j2) s += sBeta[t * 9 + j2];
                ws[WS_BT + t] = s;
            }
        }
    } else {
        int idx = (blk - 43) * 243 + t;
        if (t < 243) {
            int dx = idx % 9; int t1 = idx / 9;
            int dy = t1 % 9;  int t2 = t1 / 9;
            int ci = t2 % 3;  int c = t2 / 3;
            float s = 0.f;
            for (int a = 0; a < 3; ++a) {
                int u = dy - a; if (u < 0 || u > 6) continue;
                for (int b = 0; b < 3; ++b) {
                    int v = dx - b; if (v < 0 || v > 6) continue;
                    for (int c64 = 0; c64 < 64; ++c64)
                        s += swc2[((c * 64 + c64) * 3 + a) * 3 + b] *
                             swc1[((c64 * 3 + ci) * 7 + u) * 7 + v];
                }
            }
            ws[WS_W9 + idx] = s;   // layout c*243 + ci*81 + dy*9 + dx
        }
    }
}

// ---------------------------------------------------------------------------
// Fused conv + border-correction + trans(both modes). 20x20 tile = 2x2 patches.
// Grid (16,16,8) = 2048 blocks; LDS 18.5 KB -> 8 blocks/CU.
// sOut (coalescing buffer for bf16 rows) overlays sx in a union: sx is dead
// after phase 2 because phase-4 fea reads x straight from global (L2/L3-hot).
__global__ __launch_bounds__(256, 8) void k_fuse(const float* __restrict__ x,
                                                 const float* __restrict__ wfm,
                                                 const float* __restrict__ bfm,
                                                 const float* __restrict__ ws,
                                                 ushort* __restrict__ uiL,
                                                 ushort* __restrict__ ufL) {
    union alignas(16) SMemU {
        float  sx[3][28][36];      // 12096 B, live: stage..phase2
        ushort sOut[2][4][128];    //  2048 B, live: trans..writeout
    };
    __shared__ SMemU smu;
    __shared__ float sP[2][100][8];    // patches [ch][r][li4+pad4]
    const int bx = blockIdx.x, by = blockIdx.y, b = blockIdx.z;
    const int t = threadIdx.x;
    const float* Mt   = ws + WS_M;
    const float* Kw   = ws + WS_K;
    const float* Beta = ws + WS_BETA;
    const float* W9   = ws + WS_W9;
    const float* Bt   = ws + WS_BT;
    const int gh0 = by * 20, gw0 = bx * 20;

    // ---- stage x halo (zero-padded at image border)
    for (int idx = t; idx < 3 * 28 * 28; idx += 256) {
        int ci = idx / 784; int rem = idx - ci * 784;
        int rr = rem / 28, cc = rem - rr * 28;
        int gh = gh0 - 4 + rr, gw = gw0 - 4 + cc;
        float v = 0.f;
        if ((unsigned)gh < 320u && (unsigned)gw < 320u)
            v = x[(b * 3 + ci) * 102400 + gh * 320 + gw];
        smu.sx[ci][rr][cc] = v;
    }
    __syncthreads();

    // ---- phase 1: interior-composite 9x9 conv; 200 thr x 2 px x 2 ch
    const int lh = t / 10, lw0 = (t % 10) * 2;   // valid for t<200
    if (t < 200) {
        float acc0[2], acc1[2];
        float bt0 = Bt[0], bt1 = Bt[1];
        acc0[0] = bt0; acc0[1] = bt0; acc1[0] = bt1; acc1[1] = bt1;
        #pragma unroll
        for (int ci = 0; ci < 3; ++ci) {
            #pragma unroll
            for (int dy = 0; dy < 9; ++dy) {
                const float* xr = &smu.sx[ci][lh + dy][lw0];
                float2 y0 = *(const float2*)(xr);
                float2 y1 = *(const float2*)(xr + 2);
                float2 y2 = *(const float2*)(xr + 4);
                float2 y3 = *(const float2*)(xr + 6);
                float2 y4 = *(const float2*)(xr + 8);
                float xv[10] = {y0.x, y0.y, y1.x, y1.y, y2.x,
                                y2.y, y3.x, y3.y, y4.x, y4.y};
                #pragma unroll
                for (int dx = 0; dx < 9; ++dx) {
                    float w0t = W9[ci * 81 + dy * 9 + dx];
                    float w1t = W9[243 + ci * 81 + dy * 9 + dx];
                    acc0[0] += w0t * xv[dx];
                    acc0[1] += w0t * xv[dx + 1];
                    acc1[0] += w1t * xv[dx];
                    acc1[1] += w1t * xv[dx + 1];
                }
            }
        }
        #pragma unroll
        for (int j = 0; j < 2; ++j) {
            int lw = lw0 + j;
            int li = (lh / 10) * 2 + lw / 10;
            int r  = (lh % 10) * 10 + lw % 10;
            sP[0][r][li] = acc0[j];
            sP[1][r][li] = acc1[j];
        }
    }
    __syncthreads();

    // ---- phase 2: ring correction. exact = phase1 - sum_{invalid(a,bb)}
    // [beta_ab + K_ab (*) x_pad]; taps stay within the staged halo.
    bool edgeblk = (by == 0) | (by == 15) | (bx == 0) | (bx == 15);
    if (edgeblk) {
        for (int e = t; e < 400; e += 256) {
            int elh = e / 20, elw = e % 20;
            int h = gh0 + elh, w = gw0 + elw;
            if (h == 0 || h == 319 || w == 0 || w == 319) {
                float c0 = 0.f, c1 = 0.f;
                for (int a = 0; a < 3; ++a) {
                    int hh = h + a - 1;
                    for (int bb = 0; bb < 3; ++bb) {
                        int wwp = w + bb - 1;
                        bool invalid = ((unsigned)hh >= 320u) | ((unsigned)wwp >= 320u);
                        if (invalid) {
                            c0 += Beta[a * 3 + bb];
                            c1 += Beta[9 + a * 3 + bb];
                            for (int ci = 0; ci < 3; ++ci) {
                                const float* Kc = Kw + ((a * 3 + bb) * 3 + ci) * 49;
                                #pragma unroll
                                for (int u = 0; u < 7; ++u) {
                                    #pragma unroll
                                    for (int v = 0; v < 7; ++v) {
                                        float xv = smu.sx[ci][elh + a + u][elw + bb + v];
                                        c0 += Kc[u * 7 + v] * xv;
                                        c1 += Kc[1323 + u * 7 + v] * xv;
                                    }
                                }
                            }
                        }
                    }
                }
                int li = (elh / 10) * 2 + elw / 10;
                int r  = (elh % 10) * 10 + elw % 10;
                sP[0][r][li] -= c0;
                sP[1][r][li] -= c1;
            }
        }
    }
    __syncthreads();       // sx is DEAD from here; sOut may now use the union

    // ---- trans compute: lanes 0..199 own (plane = t/100, p = t%100);
    // acc[4] = the tile's 4 patches; results staged to sOut (bf16) for
    // coalesced row writes. Lanes 200..255 zero the p-pad [100,128).
    auto trans_compute = [&]() {
        if (t < 200) {
            int plane = (t >= 100) ? 1 : 0;
            int p = t - plane * 100;
            float acc[4] = {0.f, 0.f, 0.f, 0.f};
            #pragma unroll 4
            for (int r = 0; r < 100; ++r) {
                float m = Mt[r * 100 + p];
                f32x4 s = *(const f32x4*)&sP[plane][r][0];
                #pragma unroll
                for (int k = 0; k < 4; ++k) acc[k] += m * s[k];
            }
            #pragma unroll
            for (int k = 0; k < 4; ++k)
                smu.sOut[plane][k][p] = f2bf(fmaxf(acc[k], 0.f));
        } else {
            int task = t - 200;            // 56 tasks: 2 planes x 4 k x 7 quads
            int plane = task / 28; int rem = task % 28;
            int k = rem / 7, q = rem % 7;
            *(uint2*)&smu.sOut[plane][k][100 + q * 4] = make_uint2(0u, 0u);
        }
    };
    // coalesced writeout: 8 rows x 256 B as dwordx4
    auto writeout = [&](ushort* outL) {
        if (t < 128) {
            int row = t >> 4;              // plane*4 + k
            int plane = row >> 2, k = row & 3;
            int lane16 = t & 15;
            int bc = b * 2 + plane;
            int l = (by * 2 + (k >> 1)) * 32 + bx * 2 + (k & 1);
            uint4 v = *(const uint4*)&smu.sOut[plane][k][lane16 * 8];
            *(uint4*)&outL[((size_t)bc * 1024 + l) * 128 + lane16 * 8] = v;
        }
    };

    trans_compute();       // ---- phase 3: U_i -> sOut
    __syncthreads();
    writeout(uiL);
    // ---- phase 4 (same region): fea from GLOBAL x center (L2/L3-hot);
    // sP was fully consumed by trans_compute before the barrier above.
    if (t < 200) {
        float wf00 = wfm[0], wf01 = wfm[1], wf02 = wfm[2];
        float wf10 = wfm[3], wf11 = wfm[4], wf12 = wfm[5];
        float bf0 = bfm[0], bf1 = bfm[1];
        int gh = gh0 + lh, gwb = gw0 + lw0;
        size_t base = (size_t)b * 3 * 102400 + gh * 320 + gwb;
        float2 c0v = *(const float2*)&x[base];
        float2 c1v = *(const float2*)&x[base + 102400];
        float2 c2v = *(const float2*)&x[base + 204800];
        float s0[2] = {c0v.x, c0v.y};
        float s1[2] = {c1v.x, c1v.y};
        float s2[2] = {c2v.x, c2v.y};
        #pragma unroll
        for (int j = 0; j < 2; ++j) {
            float v0 = (bf0 + s0[j] * wf00 + s1[j] * wf01 + s2[j] * wf02) * 0.25f;
            float v1 = (bf1 + s0[j] * wf10 + s1[j] * wf11 + s2[j] * wf12) * 0.25f;
            int lw = lw0 + j;
            int li = (lh / 10) * 2 + lw / 10;
            int r  = (lh % 10) * 10 + lw % 10;
            sP[0][r][li] = v0;
            sP[1][r][li] = v1;
        }
    }
    __syncthreads();

    trans_compute();       // ---- phase 5: U_f -> sOut
    __syncthreads();
    writeout(ufL);
}

// ---------------------------------------------------------------------------
// att[bc][l][m] = (1/100) * sum_p ui[l][p]*uf[m][p], bf16 MFMA 16x16x32.
// 64x128 tile/block, grid (8,16,16) = 2048 blocks (~8/CU for TLP).
// 4 waves 2x2; each wave 32x64 = 2x4 mfma tiles.
__global__ __launch_bounds__(256) void k_att(const ushort* __restrict__ ui,
                                             const ushort* __restrict__ uf,
                                             float* __restrict__ out) {
    int bc   = blockIdx.z;
    int row0 = blockIdx.y * 64, col0 = blockIdx.x * 128;
    int wave = threadIdx.x >> 6, lane = threadIdx.x & 63;
    int r0 = row0 + (wave >> 1) * 32;
    int c0 = col0 + (wave & 1) * 64;
    int m = lane & 15, quad = lane >> 4;
    const ushort* ub = ui + (size_t)bc * 1024 * 128;
    const ushort* vb = uf + (size_t)bc * 1024 * 128;
    f32x4 acc[2][4];
    #pragma unroll
    for (int i = 0; i < 2; ++i)
        #pragma unroll
        for (int j = 0; j < 4; ++j)
            acc[i][j] = (f32x4){0.f, 0.f, 0.f, 0.f};
    #pragma unroll
    for (int k0 = 0; k0 < 128; k0 += 32) {
        bf16x8 af[2], bfr[4];
        #pragma unroll
        for (int i = 0; i < 2; ++i)
            af[i] = *(const bf16x8*)&ub[(size_t)(r0 + i * 16 + m) * 128 + k0 + quad * 8];
        #pragma unroll
        for (int j = 0; j < 4; ++j)
            bfr[j] = *(const bf16x8*)&vb[(size_t)(c0 + j * 16 + m) * 128 + k0 + quad * 8];
        #pragma unroll
        for (int i = 0; i < 2; ++i)
            #pragma unroll
            for (int j = 0; j < 4; ++j)
                acc[i][j] = __builtin_amdgcn_mfma_f32_16x16x32_bf16(af[i], bfr[j], acc[i][j], 0, 0, 0);
    }
    // C/D: col = lane&15, row = quad*4 + reg (m89/m91-verified)
    #pragma unroll
    for (int i = 0; i < 2; ++i) {
        #pragma unroll
        for (int r = 0; r < 4; ++r) {
            int row = r0 + i * 16 + quad * 4 + r;
            float* o = out + ((size_t)bc * 1024 + row) * 1024;
            #pragma unroll
            for (int j = 0; j < 4; ++j)
                o[c0 + j * 16 + m] = acc[i][j][r] * 0.01f;
        }
    }
}

extern "C" void kernel_launch(void* const* d_in, const int* in_sizes, int n_in,
                              void* d_out, int out_size, void* d_ws, size_t ws_size,
                              hipStream_t stream) {
    const float* x       = (const float*)d_in[0];
    const float* w_conv1 = (const float*)d_in[1];
    const float* b_conv1 = (const float*)d_in[2];
    const float* w_conv2 = (const float*)d_in[3];
    const float* b_conv2 = (const float*)d_in[4];
    const float* w_fm    = (const float*)d_in[5];
    const float* b_fm    = (const float*)d_in[6];
    const float* w_lin1  = (const float*)d_in[7];
    const float* w_lin2  = (const float*)d_in[8];
    float* out = (float*)d_out;
    float* ws  = (float*)d_ws;
    ushort* uiL = (ushort*)(ws + WS_UIT);
    ushort* ufL = (ushort*)(ws + WS_UFT);

    k_prep<<<45, 256, 0, stream>>>(w_lin1, w_lin2, w_conv1, b_conv1, w_conv2, b_conv2, ws);
    k_fuse<<<dim3(16, 16, 8), 256, 0, stream>>>(x, w_fm, b_fm, ws, uiL, ufL);
    k_att<<<dim3(8, 16, 16), 256, 0, stream>>>(uiL, ufL, out);
}

// Round 7
// 198.258 us; speedup vs baseline: 1.6331x; 1.0329x over previous
//
#include <hip/hip_runtime.h>

// Workspace layout (float offsets)
#define WS_M      0        // Mt[r*100+p] = M[p][r] where M = w_lin2 @ w_lin1, 10000 floats
#define WS_K      10000    // K[c][a][b][ci][u][v], 2646 floats
#define WS_BETA   12646    // beta[c][a][b], 18 floats
#define WS_W9     12664    // W9[c][ci][dy][dx], 486 floats
#define WS_BT     13150    // beta_tot[c] (interior combined bias), 2 floats
#define WS_UIT    (16384 + 1638400)      // uiL[bc][l][p128] bf16, 2,097,152 ushorts
#define WS_UFT    (16384 + 2*1638400)    // ufL[bc][l][p128] bf16

typedef short bf16x8 __attribute__((ext_vector_type(8)));
typedef float f32x4  __attribute__((ext_vector_type(4)));

__device__ inline ushort f2bf(float f) {   // round-to-nearest-even
    unsigned u = __float_as_uint(f);
    unsigned r = (u + 0x7fffu + ((u >> 16) & 1u)) >> 16;
    return (ushort)r;
}

// ---------------------------------------------------------------------------
// Prep. blocks 0..39: Mt. blocks 40..42: K (block 40 also Beta+Bt).
// blocks 43..44: W9 from raw weights.
__global__ __launch_bounds__(256) void k_prep(const float* __restrict__ wl1,
                                              const float* __restrict__ wl2,
                                              const float* __restrict__ wc1,
                                              const float* __restrict__ bc1,
                                              const float* __restrict__ wc2,
                                              const float* __restrict__ bc2,
                                              float* __restrict__ ws) {
    int blk = blockIdx.x;
    int t = threadIdx.x;
    if (blk < 40) {
        int idx = blk * 256 + t;
        if (idx < 10000) {
            int p = idx / 100, r = idx % 100;
            float s = 0.f;
            for (int q = 0; q < 200; ++q)
                s += wl2[p * 200 + q] * wl1[q * 100 + r];
            ws[WS_M + r * 100 + p] = s;
        }
        return;
    }
    __shared__ float swc1[9408];   // 64*3*49
    __shared__ float swc2[1152];   // 2*64*9
    __shared__ float sBeta[18];
    for (int i = t; i < 9408; i += 256) swc1[i] = wc1[i];
    for (int i = t; i < 1152; i += 256) swc2[i] = wc2[i];
    __syncthreads();
    if (blk < 43) {
        int base = (blk - 40) * 882;
        for (int ii = t; ii < 882; ii += 256) {
            int idx = base + ii;
            int v = idx % 7; int t1 = idx / 7;
            int u = t1 % 7;  int t2 = t1 / 7;
            int ci = t2 % 3; int t3 = t2 / 3;
            int b = t3 % 3;  int t4 = t3 / 3;
            int a = t4 % 3;  int c = t4 / 3;
            float s = 0.f;
            for (int c64 = 0; c64 < 64; ++c64)
                s += swc2[((c * 64 + c64) * 3 + a) * 3 + b] *
                     swc1[((c64 * 3 + ci) * 7 + u) * 7 + v];
            ws[WS_K + idx] = s;
        }
        if (blk == 40) {
            if (t < 18) {
                int b = t % 3; int a = (t / 3) % 3; int c = t / 9;
                float s = 0.f;
                for (int c64 = 0; c64 < 64; ++c64)
                    s += swc2[((c * 64 + c64) * 3 + a) * 3 + b] * bc1[c64];
                sBeta[t] = s; ws[WS_BETA + t] = s;
            }
            __syncthreads();
            if (t < 2) {
                float s = bc2[t];
                for (int j2 = 0; j2 < 9; ++j2) s += sBeta[t * 9 + j2];
                ws[WS_BT + t] = s;
            }
        }
    } else {
        int idx = (blk - 43) * 243 + t;
        if (t < 243) {
            int dx = idx % 9; int t1 = idx / 9;
            int dy = t1 % 9;  int t2 = t1 / 9;
            int ci = t2 % 3;  int c = t2 / 3;
            float s = 0.f;
            for (int a = 0; a < 3; ++a) {
                int u = dy - a; if (u < 0 || u > 6) continue;
                for (int b = 0; b < 3; ++b) {
                    int v = dx - b; if (v < 0 || v > 6) continue;
                    for (int c64 = 0; c64 < 64; ++c64)
                        s += swc2[((c * 64 + c64) * 3 + a) * 3 + b] *
                             swc1[((c64 * 3 + ci) * 7 + u) * 7 + v];
                }
            }
            ws[WS_W9 + idx] = s;   // layout c*243 + ci*81 + dy*9 + dx
        }
    }
}

// ---------------------------------------------------------------------------
// Fused conv + border-correction + MERGED trans (ui and uf in one Mt pass).
// 20x20 tile = 2x2 patches. Grid (16,16,8) = 2048 blocks.
// LDS 24.9 KB -> 6 blocks/CU resident, 8 blocks/CU of work (stagger).
// phase 1: W9 conv -> sP[0] AND fea (1x1, from sx) -> sP[1]
// phase 2: ring exact fix on sP[0] (edge blocks; subtract invalid-(a,b) terms)
// phase 3: single merged trans: acc_i, acc_f share each Mt load -> sOut
// phase 4: coalesced writeout of uiL and ufL (256 B rows)
__global__ __launch_bounds__(256, 6) void k_fuse(const float* __restrict__ x,
                                                 const float* __restrict__ wfm,
                                                 const float* __restrict__ bfm,
                                                 const float* __restrict__ ws,
                                                 ushort* __restrict__ uiL,
                                                 ushort* __restrict__ ufL) {
    union alignas(16) SMemU {
        float  sx[3][28][36];         // 12096 B, live: stage..phase2
        ushort sOut[2][2][4][128];    //  4096 B, live: trans..writeout
    };
    __shared__ SMemU smu;
    __shared__ float sP[2][2][100][8];   // [mat][plane][r][li4+pad4]
    const int bx = blockIdx.x, by = blockIdx.y, b = blockIdx.z;
    const int t = threadIdx.x;
    const float* Mt   = ws + WS_M;
    const float* Kw   = ws + WS_K;
    const float* Beta = ws + WS_BETA;
    const float* W9   = ws + WS_W9;
    const float* Bt   = ws + WS_BT;
    const int gh0 = by * 20, gw0 = bx * 20;
    bool edgeblk = (by == 0) | (by == 15) | (bx == 0) | (bx == 15);

    // ---- stage x halo. Interior blocks: unconditional float4 rows
    // (gw0-4 = 20bx-4 is 0 mod 4 -> aligned; 28 floats = 7x float4).
    if (!edgeblk) {
        for (int i = t; i < 588; i += 256) {         // 3*28*7
            int ci = i / 196; int rem = i - ci * 196;
            int rr = rem / 7, c4 = rem - rr * 7;
            float4 v = *(const float4*)&x[(b * 3 + ci) * 102400 +
                                          (gh0 - 4 + rr) * 320 + (gw0 - 4) + c4 * 4];
            *(float4*)&smu.sx[ci][rr][c4 * 4] = v;
        }
    } else {
        for (int idx = t; idx < 3 * 28 * 28; idx += 256) {
            int ci = idx / 784; int rem = idx - ci * 784;
            int rr = rem / 28, cc = rem - rr * 28;
            int gh = gh0 - 4 + rr, gw = gw0 - 4 + cc;
            float v = 0.f;
            if ((unsigned)gh < 320u && (unsigned)gw < 320u)
                v = x[(b * 3 + ci) * 102400 + gh * 320 + gw];
            smu.sx[ci][rr][cc] = v;
        }
    }
    __syncthreads();

    // ---- phase 1: composite 9x9 conv -> sP[0]; fea 1x1 -> sP[1]
    const int lh = t / 10, lw0 = (t % 10) * 2;   // valid for t<200
    if (t < 200) {
        float acc0[2], acc1[2];
        float bt0 = Bt[0], bt1 = Bt[1];
        acc0[0] = bt0; acc0[1] = bt0; acc1[0] = bt1; acc1[1] = bt1;
        #pragma unroll
        for (int ci = 0; ci < 3; ++ci) {
            #pragma unroll
            for (int dy = 0; dy < 9; ++dy) {
                const float* xr = &smu.sx[ci][lh + dy][lw0];
                float2 y0 = *(const float2*)(xr);
                float2 y1 = *(const float2*)(xr + 2);
                float2 y2 = *(const float2*)(xr + 4);
                float2 y3 = *(const float2*)(xr + 6);
                float2 y4 = *(const float2*)(xr + 8);
                float xv[10] = {y0.x, y0.y, y1.x, y1.y, y2.x,
                                y2.y, y3.x, y3.y, y4.x, y4.y};
                #pragma unroll
                for (int dx = 0; dx < 9; ++dx) {
                    float w0t = W9[ci * 81 + dy * 9 + dx];
                    float w1t = W9[243 + ci * 81 + dy * 9 + dx];
                    acc0[0] += w0t * xv[dx];
                    acc0[1] += w0t * xv[dx + 1];
                    acc1[0] += w1t * xv[dx];
                    acc1[1] += w1t * xv[dx + 1];
                }
            }
        }
        float wf00 = wfm[0], wf01 = wfm[1], wf02 = wfm[2];
        float wf10 = wfm[3], wf11 = wfm[4], wf12 = wfm[5];
        float bf0 = bfm[0], bf1 = bfm[1];
        #pragma unroll
        for (int j = 0; j < 2; ++j) {
            int lw = lw0 + j;
            int li = (lh / 10) * 2 + lw / 10;
            int r  = (lh % 10) * 10 + lw % 10;
            sP[0][0][r][li] = acc0[j];
            sP[0][1][r][li] = acc1[j];
            float s0 = smu.sx[0][4 + lh][4 + lw];
            float s1 = smu.sx[1][4 + lh][4 + lw];
            float s2 = smu.sx[2][4 + lh][4 + lw];
            sP[1][0][r][li] = (bf0 + s0 * wf00 + s1 * wf01 + s2 * wf02) * 0.25f;
            sP[1][1][r][li] = (bf1 + s0 * wf10 + s1 * wf11 + s2 * wf12) * 0.25f;
        }
    }
    __syncthreads();

    // ---- phase 2: ring correction on sP[0]. exact = phase1 -
    // sum_{invalid(a,bb)} [beta_ab + K_ab (*) x_pad]; taps within halo.
    if (edgeblk) {
        for (int e = t; e < 400; e += 256) {
            int elh = e / 20, elw = e % 20;
            int h = gh0 + elh, w = gw0 + elw;
            if (h == 0 || h == 319 || w == 0 || w == 319) {
                float c0 = 0.f, c1 = 0.f;
                for (int a = 0; a < 3; ++a) {
                    int hh = h + a - 1;
                    for (int bb = 0; bb < 3; ++bb) {
                        int wwp = w + bb - 1;
                        bool invalid = ((unsigned)hh >= 320u) | ((unsigned)wwp >= 320u);
                        if (invalid) {
                            c0 += Beta[a * 3 + bb];
                            c1 += Beta[9 + a * 3 + bb];
                            for (int ci = 0; ci < 3; ++ci) {
                                const float* Kc = Kw + ((a * 3 + bb) * 3 + ci) * 49;
                                #pragma unroll
                                for (int u = 0; u < 7; ++u) {
                                    #pragma unroll
                                    for (int v = 0; v < 7; ++v) {
                                        float xv = smu.sx[ci][elh + a + u][elw + bb + v];
                                        c0 += Kc[u * 7 + v] * xv;
                                        c1 += Kc[1323 + u * 7 + v] * xv;
                                    }
                                }
                            }
                        }
                    }
                }
                int li = (elh / 10) * 2 + elw / 10;
                int r  = (elh % 10) * 10 + elw % 10;
                sP[0][0][r][li] -= c0;
                sP[0][1][r][li] -= c1;
            }
        }
    }
    __syncthreads();       // sx DEAD from here; sOut takes the union

    // ---- phase 3: merged trans. Lanes 0..199: (plane,p); ONE Mt pass feeds
    // both acc_i and acc_f. Lanes 200..255: zero p-pad [100,128) in sOut.
    if (t < 200) {
        int plane = (t >= 100) ? 1 : 0;
        int p = t - plane * 100;
        float ai[4] = {0.f, 0.f, 0.f, 0.f};
        float af[4] = {0.f, 0.f, 0.f, 0.f};
        #pragma unroll 4
        for (int r = 0; r < 100; ++r) {
            float m = Mt[r * 100 + p];
            f32x4 si = *(const f32x4*)&sP[0][plane][r][0];
            f32x4 sf = *(const f32x4*)&sP[1][plane][r][0];
            #pragma unroll
            for (int k = 0; k < 4; ++k) {
                ai[k] += m * si[k];
                af[k] += m * sf[k];
            }
        }
        #pragma unroll
        for (int k = 0; k < 4; ++k) {
            smu.sOut[0][plane][k][p] = f2bf(fmaxf(ai[k], 0.f));
            smu.sOut[1][plane][k][p] = f2bf(fmaxf(af[k], 0.f));
        }
    } else {
        #pragma unroll
        for (int pass = 0; pass < 2; ++pass) {
            int task = (t - 200) + pass * 56;   // 112 tasks: mat,plane,k,q
            int mat = task / 56; int rem = task % 56;
            int plane = rem / 28; int rem2 = rem % 28;
            int k = rem2 / 7, q = rem2 % 7;
            *(uint2*)&smu.sOut[mat][plane][k][100 + q * 4] = make_uint2(0u, 0u);
        }
    }
    __syncthreads();

    // ---- phase 4: coalesced writeout, 256 thr = 2 mats x 8 rows x 16 lanes
    {
        int mat = t >> 7;
        int row = (t >> 4) & 7;
        int plane = row >> 2, k = row & 3;
        int lane16 = t & 15;
        int bc = b * 2 + plane;
        int l = (by * 2 + (k >> 1)) * 32 + bx * 2 + (k & 1);
        ushort* dst = mat ? ufL : uiL;
        uint4 v = *(const uint4*)&smu.sOut[mat][plane][k][lane16 * 8];
        *(uint4*)&dst[((size_t)bc * 1024 + l) * 128 + lane16 * 8] = v;
    }
}

// ---------------------------------------------------------------------------
// att[bc][l][m] = (1/100) * sum_p ui[l][p]*uf[m][p], bf16 MFMA 16x16x32.
// 64x128 tile/block, grid (8,16,16) = 2048 blocks (~8/CU for TLP).
// 4 waves 2x2; each wave 32x64 = 2x4 mfma tiles.
__global__ __launch_bounds__(256) void k_att(const ushort* __restrict__ ui,
                                             const ushort* __restrict__ uf,
                                             float* __restrict__ out) {
    int bc   = blockIdx.z;
    int row0 = blockIdx.y * 64, col0 = blockIdx.x * 128;
    int wave = threadIdx.x >> 6, lane = threadIdx.x & 63;
    int r0 = row0 + (wave >> 1) * 32;
    int c0 = col0 + (wave & 1) * 64;
    int m = lane & 15, quad = lane >> 4;
    const ushort* ub = ui + (size_t)bc * 1024 * 128;
    const ushort* vb = uf + (size_t)bc * 1024 * 128;
    f32x4 acc[2][4];
    #pragma unroll
    for (int i = 0; i < 2; ++i)
        #pragma unroll
        for (int j = 0; j < 4; ++j)
            acc[i][j] = (f32x4){0.f, 0.f, 0.f, 0.f};
    #pragma unroll
    for (int k0 = 0; k0 < 128; k0 += 32) {
        bf16x8 af[2], bfr[4];
        #pragma unroll
        for (int i = 0; i < 2; ++i)
            af[i] = *(const bf16x8*)&ub[(size_t)(r0 + i * 16 + m) * 128 + k0 + quad * 8];
        #pragma unroll
        for (int j = 0; j < 4; ++j)
            bfr[j] = *(const bf16x8*)&vb[(size_t)(c0 + j * 16 + m) * 128 + k0 + quad * 8];
        #pragma unroll
        for (int i = 0; i < 2; ++i)
            #pragma unroll
            for (int j = 0; j < 4; ++j)
                acc[i][j] = __builtin_amdgcn_mfma_f32_16x16x32_bf16(af[i], bfr[j], acc[i][j], 0, 0, 0);
    }
    // C/D: col = lane&15, row = quad*4 + reg (m89/m91-verified)
    #pragma unroll
    for (int i = 0; i < 2; ++i) {
        #pragma unroll
        for (int r = 0; r < 4; ++r) {
            int row = r0 + i * 16 + quad * 4 + r;
            float* o = out + ((size_t)bc * 1024 + row) * 1024;
            #pragma unroll
            for (int j = 0; j < 4; ++j)
                o[c0 + j * 16 + m] = acc[i][j][r] * 0.01f;
        }
    }
}

extern "C" void kernel_launch(void* const* d_in, const int* in_sizes, int n_in,
                              void* d_out, int out_size, void* d_ws, size_t ws_size,
                              hipStream_t stream) {
    const float* x       = (const float*)d_in[0];
    const float* w_conv1 = (const float*)d_in[1];
    const float* b_conv1 = (const float*)d_in[2];
    const float* w_conv2 = (const float*)d_in[3];
    const float* b_conv2 = (const float*)d_in[4];
    const float* w_fm    = (const float*)d_in[5];
    const float* b_fm    = (const float*)d_in[6];
    const float* w_lin1  = (const float*)d_in[7];
    const float* w_lin2  = (const float*)d_in[8];
    float* out = (float*)d_out;
    float* ws  = (float*)d_ws;
    ushort* uiL = (ushort*)(ws + WS_UIT);
    ushort* ufL = (ushort*)(ws + WS_UFT);

    k_prep<<<45, 256, 0, stream>>>(w_lin1, w_lin2, w_conv1, b_conv1, w_conv2, b_conv2, ws);
    k_fuse<<<dim3(16, 16, 8), 256, 0, stream>>>(x, w_fm, b_fm, ws, uiL, ufL);
    k_att<<<dim3(8, 16, 16), 256, 0, stream>>>(uiL, ufL, out);
}